// Round 7
// baseline (3722.187 us; speedup 1.0000x reference)
//
#include <hip/hip_runtime.h>
#include <cstdint>

#define S_TOT 15795
#define B_SZ 2
#define NQ 80
#define XSPLIT 128        // workspace sizing only
#define NSPLIT 124        // actual splits launched (124*128 >= 15795)
#define XCHUNK 128
#define MP 31616          // 31590 padded to multiple of 128

typedef __attribute__((ext_vector_type(8))) short short8;
typedef __attribute__((ext_vector_type(4))) float f32x4;
typedef __attribute__((ext_vector_type(2))) float f32x2;

__device__ __forceinline__ unsigned short f2bf(float f) {
    unsigned u = __float_as_uint(f);
    unsigned r = u + 0x7fffu + ((u >> 16) & 1u);
    return (unsigned short)(r >> 16);
}

// ---------------------------------------------------------------------------
__global__ __launch_bounds__(256)
void cast_bf16_kernel(const float* __restrict__ x, unsigned short* __restrict__ o, int n4)
{
    int i = blockIdx.x * 256 + threadIdx.x;
    if (i < n4) {
        float4 v = ((const float4*)x)[i];
        ushort4 r;
        r.x = f2bf(v.x); r.y = f2bf(v.y); r.z = f2bf(v.z); r.w = f2bf(v.w);
        ((ushort4*)o)[i] = r;
    }
}

// fused encoder init: f_out = src (fp32), b_out = bf16(src), b_mlp = bf16(src+pos)
__global__ __launch_bounds__(256)
void init_enc_kernel(const float* __restrict__ src, const float* __restrict__ pos,
                     float* __restrict__ f_out, unsigned short* __restrict__ b_out,
                     unsigned short* __restrict__ b_mlp, int n4)
{
    int i = blockIdx.x * 256 + threadIdx.x;
    if (i < n4) {
        float4 s = ((const float4*)src)[i];
        float4 p = ((const float4*)pos)[i];
        ((float4*)f_out)[i] = s;
        ushort4 r, m;
        r.x = f2bf(s.x); r.y = f2bf(s.y); r.z = f2bf(s.z); r.w = f2bf(s.w);
        m.x = f2bf(s.x + p.x); m.y = f2bf(s.y + p.y);
        m.z = f2bf(s.z + p.z); m.w = f2bf(s.w + p.w);
        ((ushort4*)b_out)[i] = r;
        ((ushort4*)b_mlp)[i] = m;
    }
}

// fused cast of encoder off(384 rows) + aw(128 rows) weights -> [6][512][256] bf16
__global__ __launch_bounds__(256)
void cast_fuse_w_kernel(const float* __restrict__ eow, const float* __restrict__ eaw,
                        unsigned short* __restrict__ o)
{
    int i = blockIdx.x * 256 + threadIdx.x;       // float4 index
    const int n4 = 6 * 512 * 256 / 4;
    if (i < n4) {
        int e = i * 4;
        int layer = e / (512 * 256);
        int rem = e - layer * 512 * 256;
        int row = rem >> 8, col = rem & 255;
        const float* src = (row < 384)
            ? eow + ((size_t)layer * 384 + row) * 256 + col
            : eaw + ((size_t)layer * 128 + (row - 384)) * 256 + col;
        float4 v = *(const float4*)src;
        ushort4 r;
        r.x = f2bf(v.x); r.y = f2bf(v.y); r.z = f2bf(v.z); r.w = f2bf(v.w);
        ((ushort4*)o)[i] = r;
    }
}

// fused bias [6][512] = eob[6][384] | eab[6][128]
__global__ __launch_bounds__(512)
void fuse_bias_kernel(const float* __restrict__ eob, const float* __restrict__ eab,
                      float* __restrict__ o)
{
    int i = blockIdx.x, t = threadIdx.x;
    o[i * 512 + t] = (t < 384) ? eob[i * 384 + t] : eab[i * 128 + (t - 384)];
}

// pack attn mask: mp[k] = 2x uint64, bit q set = blocked. coalesced via LDS.
__global__ __launch_bounds__(256)
void mask_pack_kernel(const unsigned char* __restrict__ mask,
                      unsigned long long* __restrict__ mp, int Lk)
{
    __shared__ unsigned char ml[80][260];
    const int k0 = blockIdx.x * 256;
    const int t = threadIdx.x;
    for (int idx = t; idx < 80 * 256; idx += 256) {
        int q = idx >> 8, kk = idx & 255;
        int kg = k0 + kk;
        ml[q][kk] = (kg < Lk) ? mask[(size_t)q * Lk + kg] : 1;
    }
    __syncthreads();
    int kg = k0 + t;
    if (kg < Lk) {
        unsigned long long lo = 0, hi = 0;
        #pragma unroll
        for (int q = 0; q < 64; ++q)
            lo |= (unsigned long long)(ml[q][t] ? 1u : 0u) << q;
        #pragma unroll
        for (int q = 0; q < 16; ++q)
            hi |= (unsigned long long)(ml[64 + q][t] ? 1u : 0u) << q;
        mp[2 * kg] = lo; mp[2 * kg + 1] = hi;
    }
}

// ---------------------------------------------------------------------------
// pure-bf16 MFMA GEMM, global_load_lds-staged double-buffered LDS.
// SWAPPED mfma operand order: vectorized float4/ushort4 epilogue.
__global__ __launch_bounds__(256)
void gemm_bf16_kernel(const unsigned short* __restrict__ A,
                      const unsigned short* __restrict__ B,
                      const float* __restrict__ bias, void* __restrict__ Yv,
                      int M, int N, int K, int mode)
{
    __shared__ unsigned short As[2][128 * 32];
    __shared__ unsigned short Bs[2][128 * 32];
    const int t = threadIdx.x;
    const int wave = t >> 6, lane = t & 63;
    const int quad = lane >> 4, l16 = lane & 15;
    const int bm0 = blockIdx.y * 128;
    const int bn0 = blockIdx.x * 128;
    const int wm = (wave & 1) * 64;
    const int wn = (wave >> 1) * 64;
    const int srow = t >> 2;
    const int scol = (t & 3) * 8;

    f32x4 acc[4][4] = {};

    const unsigned short* pa0 = A + (size_t)(bm0 + srow) * K + scol;
    const unsigned short* pa1 = pa0 + (size_t)64 * K;
    const unsigned short* pb0 = B + (size_t)(bn0 + srow) * K + scol;
    const unsigned short* pb1 = pb0 + (size_t)64 * K;

    #define GLL(src, dst)                                                        \
        __builtin_amdgcn_global_load_lds(                                        \
            (const __attribute__((address_space(1))) unsigned int*)(const void*)(src), \
            (__attribute__((address_space(3))) unsigned int*)(void*)(dst),       \
            16, 0, 0)

    const int nk = K / 32;
    GLL(pa0, &As[0][wave * 512]);
    GLL(pa1, &As[0][2048 + wave * 512]);
    GLL(pb0, &Bs[0][wave * 512]);
    GLL(pb1, &Bs[0][2048 + wave * 512]);
    __syncthreads();

    for (int kb = 0; kb < nk; ++kb) {
        const int cur = kb & 1, nxt = cur ^ 1;
        if (kb + 1 < nk) {
            const int k0 = (kb + 1) * 32;
            GLL(pa0 + k0, &As[nxt][wave * 512]);
            GLL(pa1 + k0, &As[nxt][2048 + wave * 512]);
            GLL(pb0 + k0, &Bs[nxt][wave * 512]);
            GLL(pb1 + k0, &Bs[nxt][2048 + wave * 512]);
        }

        short8 af[4], bf[4];
        #pragma unroll
        for (int im = 0; im < 4; ++im)
            af[im] = *(const short8*)&As[cur][(wm + im * 16 + l16) * 32 + quad * 8];
        #pragma unroll
        for (int in = 0; in < 4; ++in)
            bf[in] = *(const short8*)&Bs[cur][(wn + in * 16 + l16) * 32 + quad * 8];
        #pragma unroll
        for (int im = 0; im < 4; ++im)
            #pragma unroll
            for (int in = 0; in < 4; ++in)
                acc[im][in] = __builtin_amdgcn_mfma_f32_16x16x32_bf16(
                    bf[in], af[im], acc[im][in], 0, 0, 0);

        __syncthreads();
    }
    #undef GLL

    #pragma unroll
    for (int im = 0; im < 4; ++im) {
        const int gm = bm0 + wm + im * 16 + l16;
        if (gm >= M) continue;
        #pragma unroll
        for (int in = 0; in < 4; ++in) {
            const int gn0 = bn0 + wn + in * 16 + quad * 4;
            const float4 bv = *(const float4*)(bias + gn0);
            float o0 = acc[im][in][0] + bv.x;
            float o1 = acc[im][in][1] + bv.y;
            float o2 = acc[im][in][2] + bv.z;
            float o3 = acc[im][in][3] + bv.w;
            if (mode == 1) {
                o0 = fmaxf(o0, 0.f); o1 = fmaxf(o1, 0.f);
                o2 = fmaxf(o2, 0.f); o3 = fmaxf(o3, 0.f);
            }
            if (mode == 0) {
                float4 o = make_float4(o0, o1, o2, o3);
                *(float4*)((float*)Yv + (size_t)gm * N + gn0) = o;
            } else {
                ushort4 r4;
                r4.x = f2bf(o0); r4.y = f2bf(o1);
                r4.z = f2bf(o2); r4.w = f2bf(o3);
                *(ushort4*)((unsigned short*)Yv + (size_t)gm * N + gn0) = r4;
            }
        }
    }
}

// ---------------------------------------------------------------------------
// BM=64 variant for N==256 GEMMs: grid doubles to ~988 blocks (~3.9/CU), so
// the per-K-step vmcnt(0)+barrier drain is hidden by co-resident blocks.
// LDS 24KB, acc 32 VGPR -> co-residency grid-limited, not resource-limited.
__global__ __launch_bounds__(256)
void gemm_bf16_m64_kernel(const unsigned short* __restrict__ A,
                          const unsigned short* __restrict__ B,
                          const float* __restrict__ bias, void* __restrict__ Yv,
                          int M, int N, int K, int mode)
{
    __shared__ unsigned short As[2][64 * 32];
    __shared__ unsigned short Bs[2][128 * 32];
    const int t = threadIdx.x;
    const int wave = t >> 6, lane = t & 63;
    const int quad = lane >> 4, l16 = lane & 15;
    const int bm0 = blockIdx.y * 64;
    const int bn0 = blockIdx.x * 128;
    const int wn = wave * 32;
    const int srow = t >> 2;
    const int scol = (t & 3) * 8;

    f32x4 acc[4][2] = {};

    const unsigned short* pa0 = A + (size_t)(bm0 + srow) * K + scol;   // rows 0..63
    const unsigned short* pb0 = B + (size_t)(bn0 + srow) * K + scol;
    const unsigned short* pb1 = pb0 + (size_t)64 * K;

    #define GLL(src, dst)                                                        \
        __builtin_amdgcn_global_load_lds(                                        \
            (const __attribute__((address_space(1))) unsigned int*)(const void*)(src), \
            (__attribute__((address_space(3))) unsigned int*)(void*)(dst),       \
            16, 0, 0)

    const int nk = K / 32;
    GLL(pa0, &As[0][wave * 512]);
    GLL(pb0, &Bs[0][wave * 512]);
    GLL(pb1, &Bs[0][2048 + wave * 512]);
    __syncthreads();

    for (int kb = 0; kb < nk; ++kb) {
        const int cur = kb & 1, nxt = cur ^ 1;
        if (kb + 1 < nk) {
            const int k0 = (kb + 1) * 32;
            GLL(pa0 + k0, &As[nxt][wave * 512]);
            GLL(pb0 + k0, &Bs[nxt][wave * 512]);
            GLL(pb1 + k0, &Bs[nxt][2048 + wave * 512]);
        }

        short8 af[4], bf[2];
        #pragma unroll
        for (int im = 0; im < 4; ++im)
            af[im] = *(const short8*)&As[cur][(im * 16 + l16) * 32 + quad * 8];
        #pragma unroll
        for (int in = 0; in < 2; ++in)
            bf[in] = *(const short8*)&Bs[cur][(wn + in * 16 + l16) * 32 + quad * 8];
        #pragma unroll
        for (int im = 0; im < 4; ++im)
            #pragma unroll
            for (int in = 0; in < 2; ++in)
                acc[im][in] = __builtin_amdgcn_mfma_f32_16x16x32_bf16(
                    bf[in], af[im], acc[im][in], 0, 0, 0);

        __syncthreads();
    }
    #undef GLL

    #pragma unroll
    for (int im = 0; im < 4; ++im) {
        const int gm = bm0 + im * 16 + l16;
        if (gm >= M) continue;
        #pragma unroll
        for (int in = 0; in < 2; ++in) {
            const int gn0 = bn0 + wn + in * 16 + quad * 4;
            const float4 bv = *(const float4*)(bias + gn0);
            float o0 = acc[im][in][0] + bv.x;
            float o1 = acc[im][in][1] + bv.y;
            float o2 = acc[im][in][2] + bv.z;
            float o3 = acc[im][in][3] + bv.w;
            if (mode == 1) {
                o0 = fmaxf(o0, 0.f); o1 = fmaxf(o1, 0.f);
                o2 = fmaxf(o2, 0.f); o3 = fmaxf(o3, 0.f);
            }
            if (mode == 0) {
                float4 o = make_float4(o0, o1, o2, o3);
                *(float4*)((float*)Yv + (size_t)gm * N + gn0) = o;
            } else {
                ushort4 r4;
                r4.x = f2bf(o0); r4.y = f2bf(o1);
                r4.z = f2bf(o2); r4.w = f2bf(o3);
                *(ushort4*)((unsigned short*)Yv + (size_t)gm * N + gn0) = r4;
            }
        }
    }
}

// ---------------------------------------------------------------------------
// fp32 GEMM for small decoder matrices; optional elementwise A-add (X + Xadd).
__global__ __launch_bounds__(256)
void gemm_bias_kernel(const float* __restrict__ X, const float* __restrict__ Xadd,
                      const float* __restrict__ W,
                      const float* __restrict__ bias, float* __restrict__ Y,
                      int M, int N, int K, int relu)
{
    __shared__ float Xs[16][68];
    __shared__ float Ws[16][68];
    const int bm0 = blockIdx.y * 64;
    const int bn0 = blockIdx.x * 64;
    const int t = threadIdx.x;
    const int tx = t & 15, ty = t >> 4;
    const int lr = t >> 2;
    const int lk = (t & 3) << 2;
    float acc[4][4] = {};
    const int xr = bm0 + lr;
    const int wr = bn0 + lr;
    const float* xp = X + (size_t)xr * K + lk;
    const float* xap = Xadd ? Xadd + (size_t)xr * K + lk : nullptr;
    const float* wp = W + (size_t)wr * K + lk;
    for (int k0 = 0; k0 < K; k0 += 16) {
        float4 xv = make_float4(0.f, 0.f, 0.f, 0.f);
        if (xr < M) {
            xv = *(const float4*)(xp + k0);
            if (xap) {
                float4 av = *(const float4*)(xap + k0);
                xv.x += av.x; xv.y += av.y; xv.z += av.z; xv.w += av.w;
            }
        }
        float4 wv = make_float4(0.f, 0.f, 0.f, 0.f);
        if (wr < N) wv = *(const float4*)(wp + k0);
        Xs[lk + 0][lr] = xv.x; Xs[lk + 1][lr] = xv.y;
        Xs[lk + 2][lr] = xv.z; Xs[lk + 3][lr] = xv.w;
        Ws[lk + 0][lr] = wv.x; Ws[lk + 1][lr] = wv.y;
        Ws[lk + 2][lr] = wv.z; Ws[lk + 3][lr] = wv.w;
        __syncthreads();
        #pragma unroll
        for (int k = 0; k < 16; ++k) {
            float a0 = Xs[k][ty * 4 + 0], a1 = Xs[k][ty * 4 + 1];
            float a2 = Xs[k][ty * 4 + 2], a3 = Xs[k][ty * 4 + 3];
            float b0 = Ws[k][tx * 4 + 0], b1 = Ws[k][tx * 4 + 1];
            float b2 = Ws[k][tx * 4 + 2], b3 = Ws[k][tx * 4 + 3];
            acc[0][0] += a0 * b0; acc[0][1] += a0 * b1; acc[0][2] += a0 * b2; acc[0][3] += a0 * b3;
            acc[1][0] += a1 * b0; acc[1][1] += a1 * b1; acc[1][2] += a1 * b2; acc[1][3] += a1 * b3;
            acc[2][0] += a2 * b0; acc[2][1] += a2 * b1; acc[2][2] += a2 * b2; acc[2][3] += a2 * b3;
            acc[3][0] += a3 * b0; acc[3][1] += a3 * b1; acc[3][2] += a3 * b2; acc[3][3] += a3 * b3;
        }
        __syncthreads();
    }
    const int c0 = bn0 + tx * 4;
    float4 bv = *(const float4*)(bias + c0);
    #pragma unroll
    for (int i = 0; i < 4; ++i) {
        int r = bm0 + ty * 4 + i;
        if (r >= M) continue;
        float4 o;
        o.x = acc[i][0] + bv.x; o.y = acc[i][1] + bv.y;
        o.z = acc[i][2] + bv.z; o.w = acc[i][3] + bv.w;
        if (relu) {
            o.x = fmaxf(o.x, 0.f); o.y = fmaxf(o.y, 0.f);
            o.z = fmaxf(o.z, 0.f); o.w = fmaxf(o.w, 0.f);
        }
        *(float4*)(Y + (size_t)r * N + c0) = o;
    }
}

// ---------------------------------------------------------------------------
// LayerNorm(X + R)*g + b -> fp32 O, optional bf16 Ob, optional bf16 (O+Padd).
// float4-vectorized: lane t owns cols 4t..4t+3.
__global__ __launch_bounds__(256)
void ln_res_kernel(const float* __restrict__ X, const float* __restrict__ R,
                   const float* __restrict__ g, const float* __restrict__ bta,
                   float* __restrict__ O, unsigned short* __restrict__ Ob,
                   const float* __restrict__ Padd, unsigned short* __restrict__ Oadd,
                   int nrows)
{
    const int row = blockIdx.x * 4 + (threadIdx.x >> 6);
    if (row >= nrows) return;
    const int t = threadIdx.x & 63;
    const float4 xv = ((const float4*)(X + (size_t)row * 256))[t];
    const float4 rv = ((const float4*)(R + (size_t)row * 256))[t];
    float v0 = xv.x + rv.x, v1 = xv.y + rv.y, v2 = xv.z + rv.z, v3 = xv.w + rv.w;
    float s = v0 + v1 + v2 + v3;
    #pragma unroll
    for (int off = 32; off >= 1; off >>= 1) s += __shfl_xor(s, off, 64);
    float mu = s * (1.f / 256.f);
    float d0 = v0 - mu, d1 = v1 - mu, d2 = v2 - mu, d3 = v3 - mu;
    float s2 = d0 * d0 + d1 * d1 + d2 * d2 + d3 * d3;
    #pragma unroll
    for (int off = 32; off >= 1; off >>= 1) s2 += __shfl_xor(s2, off, 64);
    float rstd = rsqrtf(s2 * (1.f / 256.f) + 1e-5f);
    const float4 gv = ((const float4*)g)[t];
    const float4 bv = ((const float4*)bta)[t];
    float o0 = d0 * rstd * gv.x + bv.x;
    float o1 = d1 * rstd * gv.y + bv.y;
    float o2 = d2 * rstd * gv.z + bv.z;
    float o3 = d3 * rstd * gv.w + bv.w;
    ((float4*)(O + (size_t)row * 256))[t] = make_float4(o0, o1, o2, o3);
    if (Ob) {
        ushort4 r4;
        r4.x = f2bf(o0); r4.y = f2bf(o1); r4.z = f2bf(o2); r4.w = f2bf(o3);
        ((ushort4*)(Ob + (size_t)row * 256))[t] = r4;
    }
    if (Oadd) {
        const float4 pv = ((const float4*)(Padd + (size_t)row * 256))[t];
        ushort4 r4;
        r4.x = f2bf(o0 + pv.x); r4.y = f2bf(o1 + pv.y);
        r4.z = f2bf(o2 + pv.z); r4.w = f2bf(o3 + pv.w);
        ((ushort4*)(Oadd + (size_t)row * 256))[t] = r4;
    }
}

// ---------------------------------------------------------------------------
// 3D deformable attention. value bf16 [B,S,8,32]; tbl holds (w, BYTE offset);
// gather: 16B loads, v_pk_fma_f32 packed accumulate, 32-bit voffset addressing.
__global__ __launch_bounds__(256)
void deform_kernel(const float* __restrict__ offaw,
                   const unsigned short* __restrict__ value,
                   unsigned short* __restrict__ out)
{
    const int nwg = B_SZ * S_TOT;              // 31590
    const int qq = nwg >> 3, rr = nwg & 7;     // 3948, 6
    const int xcd = blockIdx.x & 7, chunk_off = blockIdx.x >> 3;
    const int bq = (xcd < rr ? xcd * (qq + 1) : rr * (qq + 1) + (xcd - rr) * qq) + chunk_off;
    const int b = bq / S_TOT;
    const int s = bq - b * S_TOT;
    const int t = threadIdx.x;

    __shared__ float2 tbl[128][9];             // [h*16+point][corner] = (w, byte_off)

    if (t < 128) {
        const int h = t >> 4, lp = t & 15, l = lp >> 2;
        float logit = offaw[(size_t)bq * 512 + 384 + t];
        float m = logit;
        m = fmaxf(m, __shfl_xor(m, 1, 64));
        m = fmaxf(m, __shfl_xor(m, 2, 64));
        m = fmaxf(m, __shfl_xor(m, 4, 64));
        m = fmaxf(m, __shfl_xor(m, 8, 64));
        float e = __expf(logit - m);
        float su = e;
        su += __shfl_xor(su, 1, 64);
        su += __shfl_xor(su, 2, 64);
        su += __shfl_xor(su, 4, 64);
        su += __shfl_xor(su, 8, 64);
        float aw = e / su;

        // constant-divisor decomposition (magic-mul per branch)
        int iz, iy, ix; float invn;
        if (s < 13824)      { invn = 1.f / 24.f; int tl = s;
                              iz = tl / 576; int r1 = tl - iz * 576;
                              iy = r1 / 24;  ix = r1 - iy * 24; }
        else if (s < 15552) { invn = 1.f / 12.f; int tl = s - 13824;
                              iz = tl / 144; int r1 = tl - iz * 144;
                              iy = r1 / 12;  ix = r1 - iy * 12; }
        else if (s < 15768) { invn = 1.f / 6.f;  int tl = s - 15552;
                              iz = tl / 36;  int r1 = tl - iz * 36;
                              iy = r1 / 6;   ix = r1 - iy * 6; }
        else                { invn = 1.f / 3.f;  int tl = s - 15768;
                              iz = tl / 9;   int r1 = tl - iz * 9;
                              iy = r1 / 3;   ix = r1 - iy * 3; }
        float rx = (ix + 0.5f) * invn;
        float ry = (iy + 0.5f) * invn;
        float rz = (iz + 0.5f) * invn;

        const int lvl_n[4]  = {24, 12, 6, 3};
        const int lvl_s0[4] = {0, 13824, 15552, 15768};
        const int nl = lvl_n[l];
        const int s0l = lvl_s0[l];
        const float* op = offaw + (size_t)bq * 512 + t * 3;
        float x = rx * nl + op[0] - 0.5f;
        float y = ry * nl + op[1] - 0.5f;
        float z = rz * nl + op[2] - 0.5f;
        float fx = floorf(x), fy = floorf(y), fz = floorf(z);
        int x0 = (int)fx, y0 = (int)fy, z0 = (int)fz;
        float wx1 = x - fx, wx0 = 1.f - wx1;
        float wy1 = y - fy, wy0 = 1.f - wy1;
        float wz1 = z - fz, wz0 = 1.f - wz1;
        int xc0 = min(max(x0, 0), nl - 1), xc1 = min(max(x0 + 1, 0), nl - 1);
        int yc0 = min(max(y0, 0), nl - 1), yc1 = min(max(y0 + 1, 0), nl - 1);
        int zc0 = min(max(z0, 0), nl - 1), zc1 = min(max(z0 + 1, 0), nl - 1);
        bool ox0 = (x0 >= 0) && (x0 < nl);
        bool ox1 = (x0 + 1 >= 0) && (x0 + 1 < nl);
        bool oy0 = (y0 >= 0) && (y0 < nl), oy1 = (y0 + 1 >= 0) && (y0 + 1 < nl);
        bool oz0 = (z0 >= 0) && (z0 < nl), oz1 = (z0 + 1 >= 0) && (z0 + 1 < nl);
        int base = b * S_TOT + s0l;
        #pragma unroll
        for (int c = 0; c < 8; ++c) {
            int dx = c & 1, dy = (c >> 1) & 1, dz = c >> 2;
            float w = (dx ? wx1 : wx0) * (dy ? wy1 : wy0) * (dz ? wz1 : wz0);
            bool ok = (dx ? ox1 : ox0) && (dy ? oy1 : oy0) && (dz ? oz1 : oz0);
            int xi = dx ? xc1 : xc0;
            int yi = dy ? yc1 : yc0;
            int zi = dz ? zc1 : zc0;
            // BYTE offset: element ((base+..)*8+h)*32, *2 bytes -> <<6
            int elem = ((base + (zi * nl + yi) * nl + xi) * 8 + h) << 6;
            tbl[t][c] = make_float2(ok ? w * aw : 0.f, __int_as_float(elem));
        }
    }
    __syncthreads();

    // gather: t = (h*8 + corner)*4 + c16; each lane loads 16B (8 bf16 ch)
    const int c16 = t & 3, z = t >> 2, cr = z & 7, h = z >> 3;
    const float2* trow = &tbl[h * 16][cr];     // +9 float2 per point row
    const unsigned cofs = (unsigned)(c16 * 16);
    f32x2 a01 = {0.f, 0.f}, a23 = {0.f, 0.f}, a45 = {0.f, 0.f}, a67 = {0.f, 0.f};
    #pragma unroll
    for (int p = 0; p < 16; ++p) {
        float2 e = trow[p * 9];
        unsigned off = __float_as_uint(e.y) + cofs;
        const uint4 dv = *(const uint4*)((const char*)value + off);
        f32x2 w2 = {e.x, e.x};
        f32x2 v01 = {__uint_as_float(dv.x << 16), __uint_as_float(dv.x & 0xffff0000u)};
        f32x2 v23 = {__uint_as_float(dv.y << 16), __uint_as_float(dv.y & 0xffff0000u)};
        f32x2 v45 = {__uint_as_float(dv.z << 16), __uint_as_float(dv.z & 0xffff0000u)};
        f32x2 v67 = {__uint_as_float(dv.w << 16), __uint_as_float(dv.w & 0xffff0000u)};
        asm("v_pk_fma_f32 %0, %1, %2, %0" : "+v"(a01) : "v"(v01), "v"(w2));
        asm("v_pk_fma_f32 %0, %1, %2, %0" : "+v"(a23) : "v"(v23), "v"(w2));
        asm("v_pk_fma_f32 %0, %1, %2, %0" : "+v"(a45) : "v"(v45), "v"(w2));
        asm("v_pk_fma_f32 %0, %1, %2, %0" : "+v"(a67) : "v"(v67), "v"(w2));
    }
    float acc[8] = {a01.x, a01.y, a23.x, a23.y, a45.x, a45.y, a67.x, a67.y};
    // butterfly reduce over corner (t bits 2..4)
    #pragma unroll
    for (int i = 0; i < 8; ++i) {
        acc[i] += __shfl_xor(acc[i], 4, 64);
        acc[i] += __shfl_xor(acc[i], 8, 64);
        acc[i] += __shfl_xor(acc[i], 16, 64);
    }
    if ((t & 28) == 0) {
        uint4 r;
        r.x = (unsigned)f2bf(acc[0]) | ((unsigned)f2bf(acc[1]) << 16);
        r.y = (unsigned)f2bf(acc[2]) | ((unsigned)f2bf(acc[3]) << 16);
        r.z = (unsigned)f2bf(acc[4]) | ((unsigned)f2bf(acc[5]) << 16);
        r.w = (unsigned)f2bf(acc[6]) | ((unsigned)f2bf(acc[7]) << 16);
        *(uint4*)(out + (size_t)bq * 256 + h * 32 + c16 * 8) = r;
    }
}

// ---------------------------------------------------------------------------
// small multi-head attention (decoder self-attn, Lk=80), online softmax.
__global__ __launch_bounds__(256)
void attn_kernel(const float* __restrict__ Q, const float* __restrict__ K,
                 const float* __restrict__ V, float* __restrict__ O,
                 int Lq, int Lk, float scale, int ldq, int ldk)
{
    const int nqc = (Lq + 3) >> 2;
    const int blk = blockIdx.x;
    const int qc = blk % nqc;
    const int bh = blk / nqc;
    const int h = bh & 7;
    const int b = bh >> 3;
    const int qi0 = qc * 4;
    const int t = threadIdx.x;
    const int c = t & 31, g = t >> 5;

    float qv[4];
    #pragma unroll
    for (int j = 0; j < 4; ++j)
        qv[j] = Q[((size_t)(b * Lq + qi0 + j)) * ldq + h * 32 + c];

    float m[4], l[4], acc[4];
    #pragma unroll
    for (int j = 0; j < 4; ++j) { m[j] = -1e30f; l[j] = 0.f; acc[j] = 0.f; }

    for (int k = g; k < Lk; k += 8) {
        float kv = K[((size_t)(b * Lk + k)) * ldk + h * 32 + c];
        float vv = V[((size_t)(b * Lk + k)) * 256 + h * 32 + c];
        #pragma unroll
        for (int j = 0; j < 4; ++j) {
            float p = qv[j] * kv;
            p += __shfl_xor(p, 16, 32);
            p += __shfl_xor(p, 8, 32);
            p += __shfl_xor(p, 4, 32);
            p += __shfl_xor(p, 2, 32);
            p += __shfl_xor(p, 1, 32);
            float sc = p * scale;
            float mn = fmaxf(m[j], sc);
            float fo = __expf(m[j] - mn);
            float w = __expf(sc - mn);
            l[j] = l[j] * fo + w;
            acc[j] = acc[j] * fo + w * vv;
            m[j] = mn;
        }
    }
    __shared__ float sm[8][4], sl[8][4], sacc[8][4][32];
    if (c == 0) {
        #pragma unroll
        for (int j = 0; j < 4; ++j) { sm[g][j] = m[j]; sl[g][j] = l[j]; }
    }
    #pragma unroll
    for (int j = 0; j < 4; ++j) sacc[g][j][c] = acc[j];
    __syncthreads();
    if (g == 0) {
        #pragma unroll
        for (int j = 0; j < 4; ++j) {
            float M = -1e30f;
            #pragma unroll
            for (int i = 0; i < 8; ++i) M = fmaxf(M, sm[i][j]);
            float L = 0.f, o = 0.f;
            #pragma unroll
            for (int i = 0; i < 8; ++i) {
                float e = __expf(sm[i][j] - M);
                L += sl[i][j] * e;
                o += sacc[i][j][c] * e;
            }
            O[((size_t)(b * Lq + qi0 + j)) * 256 + h * 32 + c] = o / L;
        }
    }
}

// ---------------------------------------------------------------------------
// split-K cross-attention phase 1, MFMA version. 5 waves x 16 queries.
__global__ __launch_bounds__(320)
void xattn_part_kernel(const float* __restrict__ Q,
                       const unsigned short* __restrict__ K,
                       const unsigned short* __restrict__ V,
                       const unsigned long long* __restrict__ mp,
                       float* __restrict__ pm, float* __restrict__ pl,
                       float* __restrict__ po, int Lk, float scale)
{
    const int split = blockIdx.x;
    const int bh = blockIdx.y;
    const int b = bh >> 3, h = bh & 7;
    const int t = threadIdx.x;
    const int wave = t >> 6, lane = t & 63;
    const int l16 = lane & 15, quad = lane >> 4;

    __shared__ unsigned short Ks[128][40];         // 10240 B (pad 40 -> 2-way banks)
    __shared__ unsigned short Vt[32][136];         //  8704 B (V transposed [ch][key])
    __shared__ unsigned short Ps[80][40];          //  6400 B (per-wave-private rows)
    __shared__ unsigned long long Mw[2][128];      //  2048 B [lo/hi][key]

    const int k_base = split * XCHUNK;

    // ---- stage K (row-major) + V (transposed) bf16, zero OOB ----
    for (int idx = t; idx < 512; idx += 320) {
        int key = idx >> 2, cg = (idx & 3) * 8;
        int kg = k_base + key;
        short8 kv = {0, 0, 0, 0, 0, 0, 0, 0};
        short8 vv = {0, 0, 0, 0, 0, 0, 0, 0};
        if (kg < Lk) {
            size_t go = ((size_t)(b * Lk + kg)) * 256 + h * 32 + cg;
            kv = *(const short8*)(K + go);
            vv = *(const short8*)(V + go);
        }
        *(short8*)&Ks[key][cg] = kv;
        #pragma unroll
        for (int j = 0; j < 8; ++j)
            Vt[cg + j][key] = (unsigned short)vv[j];
    }
    if (t < 128) {
        int kg = k_base + t;
        unsigned long long lo = ~0ULL, hi = ~0ULL;
        if (kg < Lk) { lo = mp[2 * kg]; hi = mp[2 * kg + 1]; }
        Mw[0][t] = lo; Mw[1][t] = hi;
    }

    // ---- Q fragment (bf16, pre-scaled): lane holds Q[q=l16][d=quad*8+e] ----
    const int q = wave * 16 + l16;
    short8 qf;
    {
        const float* qp = Q + ((size_t)(b * NQ + q)) * 256 + h * 32 + quad * 8;
        float4 q0 = *(const float4*)qp;
        float4 q1 = *(const float4*)(qp + 4);
        unsigned short* qh = (unsigned short*)&qf;
        qh[0] = f2bf(q0.x * scale); qh[1] = f2bf(q0.y * scale);
        qh[2] = f2bf(q0.z * scale); qh[3] = f2bf(q0.w * scale);
        qh[4] = f2bf(q1.x * scale); qh[5] = f2bf(q1.y * scale);
        qh[6] = f2bf(q1.z * scale); qh[7] = f2bf(q1.w * scale);
    }
    __syncthreads();

    // ---- QK^T: 8 key-tiles of 16 ----
    f32x4 sfr[8];
    const f32x4 zz = {0.f, 0.f, 0.f, 0.f};
    #pragma unroll
    for (int tt = 0; tt < 8; ++tt) {
        short8 kf = *(const short8*)&Ks[tt * 16 + l16][quad * 8];
        sfr[tt] = __builtin_amdgcn_mfma_f32_16x16x32_bf16(kf, qf, zz, 0, 0, 0);
    }

    // ---- mask + softmax (whole 128-key chunk at once) ----
    const unsigned long long* mrow = Mw[wave >> 2];     // waves 0-3: lo, wave 4: hi
    const int qbit = (wave < 4 ? wave * 16 : 0) + l16;
    const int widx = qbit >> 5;
    const int sh = qbit & 31;

    float sc[8][4];
    #pragma unroll
    for (int tt = 0; tt < 8; ++tt) {
        int k0 = tt * 16 + quad * 4;
        uint4 ma = *(const uint4*)&mrow[k0];
        uint4 mb = *(const uint4*)&mrow[k0 + 2];
        unsigned w0 = widx ? ma.y : ma.x;
        unsigned w1 = widx ? ma.w : ma.z;
        unsigned w2 = widx ? mb.y : mb.x;
        unsigned w3 = widx ? mb.w : mb.z;
        sc[tt][0] = ((w0 >> sh) & 1u) ? -1e9f : sfr[tt][0];
        sc[tt][1] = ((w1 >> sh) & 1u) ? -1e9f : sfr[tt][1];
        sc[tt][2] = ((w2 >> sh) & 1u) ? -1e9f : sfr[tt][2];
        sc[tt][3] = ((w3 >> sh) & 1u) ? -1e9f : sfr[tt][3];
    }
    float mx = -1e30f;
    #pragma unroll
    for (int tt = 0; tt < 8; ++tt)
        #pragma unroll
        for (int r = 0; r < 4; ++r) mx = fmaxf(mx, sc[tt][r]);
    mx = fmaxf(mx, __shfl_xor(mx, 16, 64));
    mx = fmaxf(mx, __shfl_xor(mx, 32, 64));
    float sum = 0.f;
    #pragma unroll
    for (int tt = 0; tt < 8; ++tt)
        #pragma unroll
        for (int r = 0; r < 4; ++r) {
            sc[tt][r] = __expf(sc[tt][r] - mx);
            sum += sc[tt][r];
        }
    sum += __shfl_xor(sum, 16, 64);
    sum += __shfl_xor(sum, 32, 64);

    // ---- PV: per 32-key slice, P->LDS (wave-private rows) -> MFMA ----
    f32x4 oacc[2] = {zz, zz};
    #pragma unroll
    for (int s = 0; s < 4; ++s) {
        #pragma unroll
        for (int tt = 0; tt < 2; ++tt) {
            int T = s * 2 + tt;
            unsigned plo = (unsigned)f2bf(sc[T][0]) | ((unsigned)f2bf(sc[T][1]) << 16);
            unsigned phi = (unsigned)f2bf(sc[T][2]) | ((unsigned)f2bf(sc[T][3]) << 16);
            unsigned* dst = (unsigned*)&Ps[q][tt * 16 + quad * 4];
            dst[0] = plo; dst[1] = phi;
        }
        asm volatile("" ::: "memory");   // keep LDS write->read order
        short8 pf = *(const short8*)&Ps[q][quad * 8];
        short8 vf0 = *(const short8*)&Vt[l16][s * 32 + quad * 8];
        short8 vf1 = *(const short8*)&Vt[16 + l16][s * 32 + quad * 8];
        oacc[0] = __builtin_amdgcn_mfma_f32_16x16x32_bf16(vf0, pf, oacc[0], 0, 0, 0);
        oacc[1] = __builtin_amdgcn_mfma_f32_16x16x32_bf16(vf1, pf, oacc[1], 0, 0, 0);
    }

    // ---- write partials: O^T lane holds ch=c*16+quad*4+r for q=l16 ----
    const size_t obase = ((size_t)bh * NSPLIT + split) * NQ;
    #pragma unroll
    for (int c = 0; c < 2; ++c)
        #pragma unroll
        for (int r = 0; r < 4; ++r)
            po[(obase + q) * 32 + c * 16 + quad * 4 + r] = oacc[c][r];
    if (quad == 0) { pm[obase + q] = mx; pl[obase + q] = sum; }
}

// phase 2: merge NSPLIT partials per (b,h,q) -> O[B,NQ,256]
__global__ __launch_bounds__(64)
void xattn_merge_kernel(const float* __restrict__ pm, const float* __restrict__ pl,
                        const float* __restrict__ po, float* __restrict__ O)
{
    const int idx = blockIdx.x;
    const int bh = idx / NQ, q = idx - bh * NQ;
    const int b = bh >> 3, h = bh & 7;
    const int tt = threadIdx.x;
    if (tt >= 32) return;
    const int c = tt;
    float M = -1e30f;
    for (int s = 0; s < NSPLIT; ++s)
        M = fmaxf(M, pm[((size_t)bh * NSPLIT + s) * NQ + q]);
    float L = 0.f, o = 0.f;
    for (int s = 0; s < NSPLIT; ++s) {
        size_t base = ((size_t)bh * NSPLIT + s) * NQ + q;
        float e = __expf(pm[base] - M);
        L += pl[base] * e;
        o += po[base * 32 + c] * e;
    }
    O[((size_t)(b * NQ + q)) * 256 + h * 32 + c] = o / L;
}

// ---------------------------------------------------------------------------
extern "C" void kernel_launch(void* const* d_in, const int* in_sizes, int n_in,
                              void* d_out, int out_size, void* d_ws, size_t ws_size,
                              hipStream_t stream)
{
    const float* src       = (const float*)d_in[0];
    const float* pos       = (const float*)d_in[1];
    const float* lvl_pos   = (const float*)d_in[2];
    const float* tgt       = (const float*)d_in[3];
    const float* query_pos = (const float*)d_in[4];
    const float* eow  = (const float*)d_in[6];
    const float* eob  = (const float*)d_in[7];
    const float* eaw  = (const float*)d_in[8];
    const float* eab  = (const float*)d_in[9];
    const float* evw  = (const float*)d_in[10];
    const float* evb  = (const float*)d_in[11];
    const float* eouw = (const float*)d_in[12];
    const float* eoub = (const float*)d_in[13];
    const float* el1g = (const float*)d_in[14];
    const float* el1b = (const float*)d_in[15];
    const float* ef1w = (const float*)d_in[16];
    const float* ef1b = (const float*)d_in[17];
    const float* ef2w = (const float*)d_in[18];
    const float* ef2b = (const float*)d_in[19];
    const float* el2g = (const float*)d_in[20];
    const float* el2b = (const float*)d_in[21];
    const float* dsiw = (const float*)d_in[22];
    const float* dsib = (const float*)d_in[23];
    const float* dsow = (const float*)d_in[24];
    const float* dsob = (const float*)d_in[25];
    const float* dciw = (const float*)d_in[26];
    const float* dcib = (const float*)d_in[27];
    const float* dcow = (const float*)d_in[28];
    const float* dcob = (const float*)d_in[29];
    const float* dl1g = (const float*)d_in[30];
    const float* dl1b = (const float*)d_in[31];
    const float* dl2g = (const float*)d_in[32];
    const float* dl2b = (const float*)d_in[33];
    const float* dl3g = (const float*)d_in[34];
    const float* dl3b = (const float*)d_in[35];
    const float* df1w = (const float*)d_in[36];
    const float* df1b = (const float*)d_in[37];
    const float* df2w = (const float*)d_in[38];
    const float* df2b = (const float*)d_in[39];
    const unsigned char* amask = (const unsigned char*)d_in[40];

    const int MBS = B_SZ * S_TOT;                  // 31590
    const size_t nBSC = (size_t)MBS * 256;
    const size_t nP   = (size_t)MP * 256;
    const size_t nFFA = (size_t)MBS * 512 + 16384; // packed off|aw ; aliased by b_hs

    float* ws = (float*)d_ws;
    float* f_out = ws; ws += nP;                   // encoder state / memory (fp32)
    float* f_mlp = ws; ws += nP;                   // proj output for residual
    float* f_ffa = ws; ws += nFFA;                 // f_offaw ; aliased by b_hs
    float* f_offaw = f_ffa;                        // [MBS,512] enc off|aw ; dec cross-K bf16
    float* f_val = ws; ws += nP;                   // fc2-out ; dec cross-V bf16
    float* d_q   = ws; ws += 40960;
    float* d_qkp = ws; ws += 81920;                // packed self-attn Q|K [160,512]
    float* d_sq  = ws; ws += 40960;
    float* d_sv  = ws; ws += 40960;
    float* d_ao  = ws; ws += 40960;
    float* d_pr  = ws; ws += 40960;
    float* d_h   = ws; ws += 163840;
    float* x_pm  = ws; ws += (size_t)16 * XSPLIT * NQ;
    float* x_pl  = ws; ws += (size_t)16 * XSPLIT * NQ;
    float* x_po  = ws; ws += (size_t)16 * XSPLIT * NQ * 32;
    unsigned long long* x_mp = (unsigned long long*)ws; ws += 2 * 16384;  // packed mask
    float* f_fb  = ws; ws += 6 * 512;              // fused enc off|aw bias

    unsigned short* bws = (unsigned short*)ws;
    unsigned short* b_mlp  = bws; bws += nP;            // bf16(state+pos)/dec memory+lvl_pos
    unsigned short* b_out  = bws; bws += nP;            // bf16 encoder state
    unsigned short* w_eoaw = bws; bws += (size_t)6 * 512 * 256;   // fused off|aw weights
    unsigned short* w_evw  = bws; bws += (size_t)6 * 256 * 256;
    unsigned short* w_eouw = bws; bws += (size_t)6 * 256 * 256;
    unsigned short* w_ef1  = bws; bws += (size_t)6 * 1024 * 256;
    unsigned short* w_ef2  = bws; bws += (size_t)6 * 256 * 1024;
    unsigned short* w_dciw = bws; bws += (size_t)6 * 768 * 256;

    // aliases (disjoint lifetimes):
    unsigned short* b_hs   = (unsigned short*)f_ffa;   // fc1 out (MP*1024 bf16)
    unsigned short* b_samp = b_mlp;                    // deform out (MBS*256 bf16)
    unsigned short* b_val  = (unsigned short*)x_pm;    // bf16 deform value (encoder-only;
                                                       // x_pm/x_pl/x_po = 22.3MB >= 16.2MB)
    unsigned short* b_xk   = (unsigned short*)f_offaw; // bf16 decoder cross-K [MBS,256]
    unsigned short* b_xv   = (unsigned short*)f_val;   // bf16 decoder cross-V [MBS,256]

    auto gemmb = [&](const unsigned short* A, const unsigned short* W, const float* bb,
                     void* Y, int M, int N, int K, int mode) {
        if (N == 256) {
            dim3 grid(N / 128, (M + 63) / 64);
            gemm_bf16_m64_kernel<<<grid, dim3(256), 0, stream>>>(A, W, bb, Y, M, N, K, mode);
        } else {
            dim3 grid(N / 128, (M + 127) / 128);
            gemm_bf16_kernel<<<grid, dim3(256), 0, stream>>>(A, W, bb, Y, M, N, K, mode);
        }
    };
    auto gemms = [&](const float* X, const float* Xadd, const float* W, const float* bb,
                     float* Y, int M, int N, int K, int relu) {
        dim3 grid(N / 64, (M + 63) / 64);
        gemm_bias_kernel<<<grid, dim3(256), 0, stream>>>(X, Xadd, W, bb, Y, M, N, K, relu);
    };
    auto cast = [&](const float* x, unsigned short* o, size_t n) {
        int n4c = (int)(n / 4);
        cast_bf16_kernel<<<(n4c + 255) / 256, 256, 0, stream>>>(x, o, n4c);
    };

    const int n4 = (int)(nBSC / 4);
    const float scale = 0.17677669529663687f;
    const int lnGrid = (MBS + 3) / 4;

    // one-time prep
    {
        const int nf4 = 6 * 512 * 256 / 4;
        cast_fuse_w_kernel<<<(nf4 + 255) / 256, 256, 0, stream>>>(eow, eaw, w_eoaw);
        fuse_bias_kernel<<<6, 512, 0, stream>>>(eob, eab, f_fb);
        mask_pack_kernel<<<(S_TOT + 255) / 256, 256, 0, stream>>>(amask, x_mp, S_TOT);
    }
    cast(evw,  w_evw,  (size_t)6 * 256 * 256);
    cast(eouw, w_eouw, (size_t)6 * 256 * 256);
    cast(ef1w, w_ef1,  (size_t)6 * 1024 * 256);
    cast(ef2w, w_ef2,  (size_t)6 * 256 * 1024);
    cast(dciw, w_dciw, (size_t)6 * 768 * 256);

    init_enc_kernel<<<(n4 + 255) / 256, 256, 0, stream>>>(src, pos, f_out, b_out, b_mlp, n4);

    // ---------------- encoder ----------------
    for (int i = 0; i < 6; ++i) {
        gemmb(b_mlp, w_eoaw + (size_t)i * 512 * 256, f_fb + i * 512, f_offaw, MBS, 512, 256, 0);
        gemmb(b_out, w_evw + (size_t)i * 256 * 256, evb + i * 256, b_val, MBS, 256, 256, 2);
        deform_kernel<<<MBS, 256, 0, stream>>>(f_offaw, b_val, b_samp);
        gemmb(b_samp, w_eouw + (size_t)i * 256 * 256, eoub + i * 256, f_mlp, MBS, 256, 256, 0);
        ln_res_kernel<<<lnGrid, 256, 0, stream>>>(f_out, f_mlp, el1g + i * 256, el1b + i * 256,
                                                  f_out, b_out, (const float*)nullptr,
                                                  (unsigned short*)nullptr, MBS);
        gemmb(b_out, w_ef1 + (size_t)i * 1024 * 256, ef1b + i * 1024, b_hs, MBS, 1024, 256, 1);
        gemmb(b_hs, w_ef2 + (size_t)i * 256 * 1024, ef2b + i * 256, f_val, MBS, 256, 1024, 0);
        ln_res_kernel<<<lnGrid, 256, 0, stream>>>(f_out, f_val, el2g + i * 256, el2b + i * 256,
                                                  f_out, b_out, (i < 5 ? pos : lvl_pos),
                                                  b_mlp, MBS);
    }

    // ---------------- decoder ----------------
    hipMemcpyAsync(d_q, tgt, 40960 * sizeof(float), hipMemcpyDeviceToDevice, stream);

    for (int i = 0; i < 6; ++i) {
        const float* siw = dsiw + (size_t)i * 768 * 256;
        const float* sib = dsib + (size_t)i * 768;
        gemms(d_q, query_pos, siw, sib, d_qkp, 160, 512, 256, 0);        // packed Q|K
        gemms(d_q, nullptr, siw + 512 * 256, sib + 512, d_sv, 160, 256, 256, 0);
        attn_kernel<<<B_SZ * 8 * (NQ / 4), 256, 0, stream>>>(
            d_qkp, d_qkp + 256, d_sv, d_ao, NQ, NQ, scale, 512, 512);
        gemms(d_ao, nullptr, dsow + (size_t)i * 256 * 256, dsob + i * 256, d_pr, 160, 256, 256, 0);
        ln_res_kernel<<<40, 256, 0, stream>>>(d_q, d_pr, dl2g + i * 256, dl2b + i * 256,
                                              d_q, (unsigned short*)nullptr,
                                              (const float*)nullptr, (unsigned short*)nullptr, 160);

        const float* cib = dcib + (size_t)i * 768;
        gemms(d_q, query_pos, dciw + (size_t)i * 768 * 256, cib, d_sq, 160, 256, 256, 0);
        gemmb(b_mlp, w_dciw + (size_t)i * 768 * 256 + 256 * 256, cib + 256,
              b_xk, MBS, 256, 256, 2);                                         // cross-K bf16
        gemmb(b_out, w_dciw + (size_t)i * 768 * 256 + 512 * 256, cib + 512,
              b_xv, MBS, 256, 256, 2);                                         // cross-V bf16
        xattn_part_kernel<<<dim3(NSPLIT, 16), 320, 0, stream>>>(
            d_sq, b_xk, b_xv, x_mp, x_pm, x_pl, x_po, S_TOT, scale);
        xattn_merge_kernel<<<16 * NQ, 64, 0, stream>>>(x_pm, x_pl, x_po, d_ao);
        gemms(d_ao, nullptr, dcow + (size_t)i * 256 * 256, dcob + i * 256, d_pr, 160, 256, 256, 0);
        ln_res_kernel<<<40, 256, 0, stream>>>(d_q, d_pr, dl1g + i * 256, dl1b + i * 256,
                                              d_q, (unsigned short*)nullptr,
                                              (const float*)nullptr, (unsigned short*)nullptr, 160);

        gemms(d_q, nullptr, df1w + (size_t)i * 1024 * 256, df1b + i * 1024, d_h, 160, 1024, 256, 1);
        gemms(d_h, nullptr, df2w + (size_t)i * 256 * 1024, df2b + i * 256, d_pr, 160, 256, 1024, 0);
        ln_res_kernel<<<40, 256, 0, stream>>>(d_q, d_pr, dl3g + i * 256, dl3b + i * 256,
                                              d_q, (unsigned short*)nullptr,
                                              (const float*)nullptr, (unsigned short*)nullptr, 160);
    }

    hipMemcpyAsync(d_out, d_q, 40960 * sizeof(float), hipMemcpyDeviceToDevice, stream);
}

// Round 8
// 3653.177 us; speedup vs baseline: 1.0189x; 1.0189x over previous
//
#include <hip/hip_runtime.h>
#include <cstdint>

#define S_TOT 15795
#define B_SZ 2
#define NQ 80
#define XSPLIT 128        // workspace sizing only
#define NSPLIT 124        // actual splits launched (124*128 >= 15795)
#define XCHUNK 128
#define MP 31616          // 31590 padded to multiple of 128

typedef __attribute__((ext_vector_type(8))) short short8;
typedef __attribute__((ext_vector_type(4))) float f32x4;
typedef __attribute__((ext_vector_type(2))) float f32x2;

__device__ __forceinline__ unsigned short f2bf(float f) {
    unsigned u = __float_as_uint(f);
    unsigned r = u + 0x7fffu + ((u >> 16) & 1u);
    return (unsigned short)(r >> 16);
}

// ---------------------------------------------------------------------------
__global__ __launch_bounds__(256)
void cast_bf16_kernel(const float* __restrict__ x, unsigned short* __restrict__ o, int n4)
{
    int i = blockIdx.x * 256 + threadIdx.x;
    if (i < n4) {
        float4 v = ((const float4*)x)[i];
        ushort4 r;
        r.x = f2bf(v.x); r.y = f2bf(v.y); r.z = f2bf(v.z); r.w = f2bf(v.w);
        ((ushort4*)o)[i] = r;
    }
}

// fused encoder init: f_out = src (fp32), b_out = bf16(src), b_mlp = bf16(src+pos)
__global__ __launch_bounds__(256)
void init_enc_kernel(const float* __restrict__ src, const float* __restrict__ pos,
                     float* __restrict__ f_out, unsigned short* __restrict__ b_out,
                     unsigned short* __restrict__ b_mlp, int n4)
{
    int i = blockIdx.x * 256 + threadIdx.x;
    if (i < n4) {
        float4 s = ((const float4*)src)[i];
        float4 p = ((const float4*)pos)[i];
        ((float4*)f_out)[i] = s;
        ushort4 r, m;
        r.x = f2bf(s.x); r.y = f2bf(s.y); r.z = f2bf(s.z); r.w = f2bf(s.w);
        m.x = f2bf(s.x + p.x); m.y = f2bf(s.y + p.y);
        m.z = f2bf(s.z + p.z); m.w = f2bf(s.w + p.w);
        ((ushort4*)b_out)[i] = r;
        ((ushort4*)b_mlp)[i] = m;
    }
}

// fused cast of encoder off(384 rows) + aw(128 rows) weights -> [6][512][256] bf16
__global__ __launch_bounds__(256)
void cast_fuse_w_kernel(const float* __restrict__ eow, const float* __restrict__ eaw,
                        unsigned short* __restrict__ o)
{
    int i = blockIdx.x * 256 + threadIdx.x;       // float4 index
    const int n4 = 6 * 512 * 256 / 4;
    if (i < n4) {
        int e = i * 4;
        int layer = e / (512 * 256);
        int rem = e - layer * 512 * 256;
        int row = rem >> 8, col = rem & 255;
        const float* src = (row < 384)
            ? eow + ((size_t)layer * 384 + row) * 256 + col
            : eaw + ((size_t)layer * 128 + (row - 384)) * 256 + col;
        float4 v = *(const float4*)src;
        ushort4 r;
        r.x = f2bf(v.x); r.y = f2bf(v.y); r.z = f2bf(v.z); r.w = f2bf(v.w);
        ((ushort4*)o)[i] = r;
    }
}

// fused bias [6][512] = eob[6][384] | eab[6][128]
__global__ __launch_bounds__(512)
void fuse_bias_kernel(const float* __restrict__ eob, const float* __restrict__ eab,
                      float* __restrict__ o)
{
    int i = blockIdx.x, t = threadIdx.x;
    o[i * 512 + t] = (t < 384) ? eob[i * 384 + t] : eab[i * 128 + (t - 384)];
}

// pack attn mask: mp[k] = 2x uint64, bit q set = blocked. coalesced via LDS.
__global__ __launch_bounds__(256)
void mask_pack_kernel(const unsigned char* __restrict__ mask,
                      unsigned long long* __restrict__ mp, int Lk)
{
    __shared__ unsigned char ml[80][260];
    const int k0 = blockIdx.x * 256;
    const int t = threadIdx.x;
    for (int idx = t; idx < 80 * 256; idx += 256) {
        int q = idx >> 8, kk = idx & 255;
        int kg = k0 + kk;
        ml[q][kk] = (kg < Lk) ? mask[(size_t)q * Lk + kg] : 1;
    }
    __syncthreads();
    int kg = k0 + t;
    if (kg < Lk) {
        unsigned long long lo = 0, hi = 0;
        #pragma unroll
        for (int q = 0; q < 64; ++q)
            lo |= (unsigned long long)(ml[q][t] ? 1u : 0u) << q;
        #pragma unroll
        for (int q = 0; q < 16; ++q)
            hi |= (unsigned long long)(ml[64 + q][t] ? 1u : 0u) << q;
        mp[2 * kg] = lo; mp[2 * kg + 1] = hi;
    }
}

// ---------------------------------------------------------------------------
// pure-bf16 MFMA GEMM, global_load_lds-staged double-buffered LDS.
// SWAPPED mfma operand order: vectorized float4/ushort4 epilogue.
__global__ __launch_bounds__(256)
void gemm_bf16_kernel(const unsigned short* __restrict__ A,
                      const unsigned short* __restrict__ B,
                      const float* __restrict__ bias, void* __restrict__ Yv,
                      int M, int N, int K, int mode)
{
    __shared__ unsigned short As[2][128 * 32];
    __shared__ unsigned short Bs[2][128 * 32];
    const int t = threadIdx.x;
    const int wave = t >> 6, lane = t & 63;
    const int quad = lane >> 4, l16 = lane & 15;
    const int bm0 = blockIdx.y * 128;
    const int bn0 = blockIdx.x * 128;
    const int wm = (wave & 1) * 64;
    const int wn = (wave >> 1) * 64;
    const int srow = t >> 2;
    const int scol = (t & 3) * 8;

    f32x4 acc[4][4] = {};

    const unsigned short* pa0 = A + (size_t)(bm0 + srow) * K + scol;
    const unsigned short* pa1 = pa0 + (size_t)64 * K;
    const unsigned short* pb0 = B + (size_t)(bn0 + srow) * K + scol;
    const unsigned short* pb1 = pb0 + (size_t)64 * K;

    #define GLL(src, dst)                                                        \
        __builtin_amdgcn_global_load_lds(                                        \
            (const __attribute__((address_space(1))) unsigned int*)(const void*)(src), \
            (__attribute__((address_space(3))) unsigned int*)(void*)(dst),       \
            16, 0, 0)

    const int nk = K / 32;
    GLL(pa0, &As[0][wave * 512]);
    GLL(pa1, &As[0][2048 + wave * 512]);
    GLL(pb0, &Bs[0][wave * 512]);
    GLL(pb1, &Bs[0][2048 + wave * 512]);
    __syncthreads();

    for (int kb = 0; kb < nk; ++kb) {
        const int cur = kb & 1, nxt = cur ^ 1;
        if (kb + 1 < nk) {
            const int k0 = (kb + 1) * 32;
            GLL(pa0 + k0, &As[nxt][wave * 512]);
            GLL(pa1 + k0, &As[nxt][2048 + wave * 512]);
            GLL(pb0 + k0, &Bs[nxt][wave * 512]);
            GLL(pb1 + k0, &Bs[nxt][2048 + wave * 512]);
        }

        short8 af[4], bf[4];
        #pragma unroll
        for (int im = 0; im < 4; ++im)
            af[im] = *(const short8*)&As[cur][(wm + im * 16 + l16) * 32 + quad * 8];
        #pragma unroll
        for (int in = 0; in < 4; ++in)
            bf[in] = *(const short8*)&Bs[cur][(wn + in * 16 + l16) * 32 + quad * 8];
        #pragma unroll
        for (int im = 0; im < 4; ++im)
            #pragma unroll
            for (int in = 0; in < 4; ++in)
                acc[im][in] = __builtin_amdgcn_mfma_f32_16x16x32_bf16(
                    bf[in], af[im], acc[im][in], 0, 0, 0);

        __syncthreads();
    }
    #undef GLL

    #pragma unroll
    for (int im = 0; im < 4; ++im) {
        const int gm = bm0 + wm + im * 16 + l16;
        if (gm >= M) continue;
        #pragma unroll
        for (int in = 0; in < 4; ++in) {
            const int gn0 = bn0 + wn + in * 16 + quad * 4;
            const float4 bv = *(const float4*)(bias + gn0);
            float o0 = acc[im][in][0] + bv.x;
            float o1 = acc[im][in][1] + bv.y;
            float o2 = acc[im][in][2] + bv.z;
            float o3 = acc[im][in][3] + bv.w;
            if (mode == 1) {
                o0 = fmaxf(o0, 0.f); o1 = fmaxf(o1, 0.f);
                o2 = fmaxf(o2, 0.f); o3 = fmaxf(o3, 0.f);
            }
            if (mode == 0) {
                float4 o = make_float4(o0, o1, o2, o3);
                *(float4*)((float*)Yv + (size_t)gm * N + gn0) = o;
            } else {
                ushort4 r4;
                r4.x = f2bf(o0); r4.y = f2bf(o1);
                r4.z = f2bf(o2); r4.w = f2bf(o3);
                *(ushort4*)((unsigned short*)Yv + (size_t)gm * N + gn0) = r4;
            }
        }
    }
}

// ---------------------------------------------------------------------------
// FUSED GEMM (N=256) + bias + residual + LayerNorm. BM=64 x BN=256 tile:
// each output row lives in ONE wave (lane quad,l16 -> row l16, cols
// in*16+quad*4+r), so the 256-col LN reduce is 64 in-reg adds + 2 shfl_xor
// over the quad bits. Writes Fout (fp32 residual stream) + Bout (bf16)
// [+ Oadd = bf16(out + Padd)]. Eliminates the separate ln_res pass and the
// 32MB fp32 intermediate.
__global__ __launch_bounds__(256)
void gemm_ln_kernel(const unsigned short* __restrict__ A,
                    const unsigned short* __restrict__ B,
                    const float* __restrict__ bias,
                    const float* __restrict__ g, const float* __restrict__ bta,
                    float* __restrict__ Fout, unsigned short* __restrict__ Bout,
                    const float* __restrict__ Padd, unsigned short* __restrict__ Oadd,
                    int M, int K)
{
    __shared__ unsigned short As[2][64 * 32];      //  8 KB
    __shared__ unsigned short Bs[2][256 * 32];     // 32 KB
    const int t = threadIdx.x;
    const int wave = t >> 6, lane = t & 63;
    const int quad = lane >> 4, l16 = lane & 15;
    const int bm0 = blockIdx.x * 64;

    f32x4 acc[16] = {};

    const int srow4 = lane >> 2;                   // 0..15
    const int scol = (lane & 3) * 8;
    const unsigned short* pa = A + (size_t)(bm0 + wave * 16 + srow4) * K + scol;
    const unsigned short* pb = B + (size_t)(wave * 64 + srow4) * K + scol;

    #define GLL(src, dst)                                                        \
        __builtin_amdgcn_global_load_lds(                                        \
            (const __attribute__((address_space(1))) unsigned int*)(const void*)(src), \
            (__attribute__((address_space(3))) unsigned int*)(void*)(dst),       \
            16, 0, 0)

    const int nk = K / 32;
    GLL(pa, (char*)As[0] + wave * 1024);
    #pragma unroll
    for (int j = 0; j < 4; ++j)
        GLL(pb + (size_t)j * 16 * K, (char*)Bs[0] + (wave * 4 + j) * 1024);
    __syncthreads();

    for (int kb = 0; kb < nk; ++kb) {
        const int cur = kb & 1, nxt = cur ^ 1;
        if (kb + 1 < nk) {
            const int k0 = (kb + 1) * 32;
            GLL(pa + k0, (char*)As[nxt] + wave * 1024);
            #pragma unroll
            for (int j = 0; j < 4; ++j)
                GLL(pb + (size_t)j * 16 * K + k0, (char*)Bs[nxt] + (wave * 4 + j) * 1024);
        }

        short8 af = *(const short8*)&As[cur][(wave * 16 + l16) * 32 + quad * 8];
        #pragma unroll
        for (int in = 0; in < 16; ++in) {
            short8 bf = *(const short8*)&Bs[cur][(in * 16 + l16) * 32 + quad * 8];
            acc[in] = __builtin_amdgcn_mfma_f32_16x16x32_bf16(bf, af, acc[in], 0, 0, 0);
        }
        __syncthreads();
    }
    #undef GLL

    const int row = bm0 + wave * 16 + l16;
    if (row >= M) return;                          // quad-uniform -> shfl-safe

    // bias + residual; accumulate row sum
    float s = 0.f;
    #pragma unroll
    for (int in = 0; in < 16; ++in) {
        const int c0 = in * 16 + quad * 4;
        const float4 bv = *(const float4*)(bias + c0);
        const float4 rv = *(const float4*)(Fout + (size_t)row * 256 + c0);
        acc[in][0] += bv.x + rv.x;
        acc[in][1] += bv.y + rv.y;
        acc[in][2] += bv.z + rv.z;
        acc[in][3] += bv.w + rv.w;
        s += acc[in][0] + acc[in][1] + acc[in][2] + acc[in][3];
    }
    s += __shfl_xor(s, 16, 64);
    s += __shfl_xor(s, 32, 64);
    const float mu = s * (1.f / 256.f);
    float s2 = 0.f;
    #pragma unroll
    for (int in = 0; in < 16; ++in) {
        float d0 = acc[in][0] - mu, d1 = acc[in][1] - mu;
        float d2 = acc[in][2] - mu, d3 = acc[in][3] - mu;
        s2 += d0 * d0 + d1 * d1 + d2 * d2 + d3 * d3;
    }
    s2 += __shfl_xor(s2, 16, 64);
    s2 += __shfl_xor(s2, 32, 64);
    const float rstd = rsqrtf(s2 * (1.f / 256.f) + 1e-5f);

    #pragma unroll
    for (int in = 0; in < 16; ++in) {
        const int c0 = in * 16 + quad * 4;
        const float4 gv = *(const float4*)(g + c0);
        const float4 bt = *(const float4*)(bta + c0);
        float o0 = (acc[in][0] - mu) * rstd * gv.x + bt.x;
        float o1 = (acc[in][1] - mu) * rstd * gv.y + bt.y;
        float o2 = (acc[in][2] - mu) * rstd * gv.z + bt.z;
        float o3 = (acc[in][3] - mu) * rstd * gv.w + bt.w;
        *(float4*)(Fout + (size_t)row * 256 + c0) = make_float4(o0, o1, o2, o3);
        ushort4 r4;
        r4.x = f2bf(o0); r4.y = f2bf(o1); r4.z = f2bf(o2); r4.w = f2bf(o3);
        *(ushort4*)(Bout + (size_t)row * 256 + c0) = r4;
        if (Oadd) {
            const float4 pv = *(const float4*)(Padd + (size_t)row * 256 + c0);
            ushort4 a4;
            a4.x = f2bf(o0 + pv.x); a4.y = f2bf(o1 + pv.y);
            a4.z = f2bf(o2 + pv.z); a4.w = f2bf(o3 + pv.w);
            *(ushort4*)(Oadd + (size_t)row * 256 + c0) = a4;
        }
    }
}

// ---------------------------------------------------------------------------
// fp32 GEMM for small decoder matrices; optional elementwise A-add (X + Xadd).
__global__ __launch_bounds__(256)
void gemm_bias_kernel(const float* __restrict__ X, const float* __restrict__ Xadd,
                      const float* __restrict__ W,
                      const float* __restrict__ bias, float* __restrict__ Y,
                      int M, int N, int K, int relu)
{
    __shared__ float Xs[16][68];
    __shared__ float Ws[16][68];
    const int bm0 = blockIdx.y * 64;
    const int bn0 = blockIdx.x * 64;
    const int t = threadIdx.x;
    const int tx = t & 15, ty = t >> 4;
    const int lr = t >> 2;
    const int lk = (t & 3) << 2;
    float acc[4][4] = {};
    const int xr = bm0 + lr;
    const int wr = bn0 + lr;
    const float* xp = X + (size_t)xr * K + lk;
    const float* xap = Xadd ? Xadd + (size_t)xr * K + lk : nullptr;
    const float* wp = W + (size_t)wr * K + lk;
    for (int k0 = 0; k0 < K; k0 += 16) {
        float4 xv = make_float4(0.f, 0.f, 0.f, 0.f);
        if (xr < M) {
            xv = *(const float4*)(xp + k0);
            if (xap) {
                float4 av = *(const float4*)(xap + k0);
                xv.x += av.x; xv.y += av.y; xv.z += av.z; xv.w += av.w;
            }
        }
        float4 wv = make_float4(0.f, 0.f, 0.f, 0.f);
        if (wr < N) wv = *(const float4*)(wp + k0);
        Xs[lk + 0][lr] = xv.x; Xs[lk + 1][lr] = xv.y;
        Xs[lk + 2][lr] = xv.z; Xs[lk + 3][lr] = xv.w;
        Ws[lk + 0][lr] = wv.x; Ws[lk + 1][lr] = wv.y;
        Ws[lk + 2][lr] = wv.z; Ws[lk + 3][lr] = wv.w;
        __syncthreads();
        #pragma unroll
        for (int k = 0; k < 16; ++k) {
            float a0 = Xs[k][ty * 4 + 0], a1 = Xs[k][ty * 4 + 1];
            float a2 = Xs[k][ty * 4 + 2], a3 = Xs[k][ty * 4 + 3];
            float b0 = Ws[k][tx * 4 + 0], b1 = Ws[k][tx * 4 + 1];
            float b2 = Ws[k][tx * 4 + 2], b3 = Ws[k][tx * 4 + 3];
            acc[0][0] += a0 * b0; acc[0][1] += a0 * b1; acc[0][2] += a0 * b2; acc[0][3] += a0 * b3;
            acc[1][0] += a1 * b0; acc[1][1] += a1 * b1; acc[1][2] += a1 * b2; acc[1][3] += a1 * b3;
            acc[2][0] += a2 * b0; acc[2][1] += a2 * b1; acc[2][2] += a2 * b2; acc[2][3] += a2 * b3;
            acc[3][0] += a3 * b0; acc[3][1] += a3 * b1; acc[3][2] += a3 * b2; acc[3][3] += a3 * b3;
        }
        __syncthreads();
    }
    const int c0 = bn0 + tx * 4;
    float4 bv = *(const float4*)(bias + c0);
    #pragma unroll
    for (int i = 0; i < 4; ++i) {
        int r = bm0 + ty * 4 + i;
        if (r >= M) continue;
        float4 o;
        o.x = acc[i][0] + bv.x; o.y = acc[i][1] + bv.y;
        o.z = acc[i][2] + bv.z; o.w = acc[i][3] + bv.w;
        if (relu) {
            o.x = fmaxf(o.x, 0.f); o.y = fmaxf(o.y, 0.f);
            o.z = fmaxf(o.z, 0.f); o.w = fmaxf(o.w, 0.f);
        }
        *(float4*)(Y + (size_t)r * N + c0) = o;
    }
}

// ---------------------------------------------------------------------------
// LayerNorm(X + R)*g + b -> fp32 O, optional bf16 Ob, optional bf16 (O+Padd).
// float4-vectorized: lane t owns cols 4t..4t+3.  (decoder-only now)
__global__ __launch_bounds__(256)
void ln_res_kernel(const float* __restrict__ X, const float* __restrict__ R,
                   const float* __restrict__ g, const float* __restrict__ bta,
                   float* __restrict__ O, unsigned short* __restrict__ Ob,
                   const float* __restrict__ Padd, unsigned short* __restrict__ Oadd,
                   int nrows)
{
    const int row = blockIdx.x * 4 + (threadIdx.x >> 6);
    if (row >= nrows) return;
    const int t = threadIdx.x & 63;
    const float4 xv = ((const float4*)(X + (size_t)row * 256))[t];
    const float4 rv = ((const float4*)(R + (size_t)row * 256))[t];
    float v0 = xv.x + rv.x, v1 = xv.y + rv.y, v2 = xv.z + rv.z, v3 = xv.w + rv.w;
    float s = v0 + v1 + v2 + v3;
    #pragma unroll
    for (int off = 32; off >= 1; off >>= 1) s += __shfl_xor(s, off, 64);
    float mu = s * (1.f / 256.f);
    float d0 = v0 - mu, d1 = v1 - mu, d2 = v2 - mu, d3 = v3 - mu;
    float s2 = d0 * d0 + d1 * d1 + d2 * d2 + d3 * d3;
    #pragma unroll
    for (int off = 32; off >= 1; off >>= 1) s2 += __shfl_xor(s2, off, 64);
    float rstd = rsqrtf(s2 * (1.f / 256.f) + 1e-5f);
    const float4 gv = ((const float4*)g)[t];
    const float4 bv = ((const float4*)bta)[t];
    float o0 = d0 * rstd * gv.x + bv.x;
    float o1 = d1 * rstd * gv.y + bv.y;
    float o2 = d2 * rstd * gv.z + bv.z;
    float o3 = d3 * rstd * gv.w + bv.w;
    ((float4*)(O + (size_t)row * 256))[t] = make_float4(o0, o1, o2, o3);
    if (Ob) {
        ushort4 r4;
        r4.x = f2bf(o0); r4.y = f2bf(o1); r4.z = f2bf(o2); r4.w = f2bf(o3);
        ((ushort4*)(Ob + (size_t)row * 256))[t] = r4;
    }
    if (Oadd) {
        const float4 pv = ((const float4*)(Padd + (size_t)row * 256))[t];
        ushort4 r4;
        r4.x = f2bf(o0 + pv.x); r4.y = f2bf(o1 + pv.y);
        r4.z = f2bf(o2 + pv.z); r4.w = f2bf(o3 + pv.w);
        ((ushort4*)(Oadd + (size_t)row * 256))[t] = r4;
    }
}

// ---------------------------------------------------------------------------
// 3D deformable attention. value bf16 [B,S,8,32]; tbl holds (w, BYTE offset);
// gather: 16B loads, v_pk_fma_f32 packed accumulate, 32-bit voffset addressing.
__global__ __launch_bounds__(256)
void deform_kernel(const float* __restrict__ offaw,
                   const unsigned short* __restrict__ value,
                   unsigned short* __restrict__ out)
{
    const int nwg = B_SZ * S_TOT;              // 31590
    const int qq = nwg >> 3, rr = nwg & 7;     // 3948, 6
    const int xcd = blockIdx.x & 7, chunk_off = blockIdx.x >> 3;
    const int bq = (xcd < rr ? xcd * (qq + 1) : rr * (qq + 1) + (xcd - rr) * qq) + chunk_off;
    const int b = bq / S_TOT;
    const int s = bq - b * S_TOT;
    const int t = threadIdx.x;

    __shared__ float2 tbl[128][9];             // [h*16+point][corner] = (w, byte_off)

    if (t < 128) {
        const int h = t >> 4, lp = t & 15, l = lp >> 2;
        float logit = offaw[(size_t)bq * 512 + 384 + t];
        float m = logit;
        m = fmaxf(m, __shfl_xor(m, 1, 64));
        m = fmaxf(m, __shfl_xor(m, 2, 64));
        m = fmaxf(m, __shfl_xor(m, 4, 64));
        m = fmaxf(m, __shfl_xor(m, 8, 64));
        float e = __expf(logit - m);
        float su = e;
        su += __shfl_xor(su, 1, 64);
        su += __shfl_xor(su, 2, 64);
        su += __shfl_xor(su, 4, 64);
        su += __shfl_xor(su, 8, 64);
        float aw = e / su;

        // constant-divisor decomposition (magic-mul per branch)
        int iz, iy, ix; float invn;
        if (s < 13824)      { invn = 1.f / 24.f; int tl = s;
                              iz = tl / 576; int r1 = tl - iz * 576;
                              iy = r1 / 24;  ix = r1 - iy * 24; }
        else if (s < 15552) { invn = 1.f / 12.f; int tl = s - 13824;
                              iz = tl / 144; int r1 = tl - iz * 144;
                              iy = r1 / 12;  ix = r1 - iy * 12; }
        else if (s < 15768) { invn = 1.f / 6.f;  int tl = s - 15552;
                              iz = tl / 36;  int r1 = tl - iz * 36;
                              iy = r1 / 6;   ix = r1 - iy * 6; }
        else                { invn = 1.f / 3.f;  int tl = s - 15768;
                              iz = tl / 9;   int r1 = tl - iz * 9;
                              iy = r1 / 3;   ix = r1 - iy * 3; }
        float rx = (ix + 0.5f) * invn;
        float ry = (iy + 0.5f) * invn;
        float rz = (iz + 0.5f) * invn;

        const int lvl_n[4]  = {24, 12, 6, 3};
        const int lvl_s0[4] = {0, 13824, 15552, 15768};
        const int nl = lvl_n[l];
        const int s0l = lvl_s0[l];
        const float* op = offaw + (size_t)bq * 512 + t * 3;
        float x = rx * nl + op[0] - 0.5f;
        float y = ry * nl + op[1] - 0.5f;
        float z = rz * nl + op[2] - 0.5f;
        float fx = floorf(x), fy = floorf(y), fz = floorf(z);
        int x0 = (int)fx, y0 = (int)fy, z0 = (int)fz;
        float wx1 = x - fx, wx0 = 1.f - wx1;
        float wy1 = y - fy, wy0 = 1.f - wy1;
        float wz1 = z - fz, wz0 = 1.f - wz1;
        int xc0 = min(max(x0, 0), nl - 1), xc1 = min(max(x0 + 1, 0), nl - 1);
        int yc0 = min(max(y0, 0), nl - 1), yc1 = min(max(y0 + 1, 0), nl - 1);
        int zc0 = min(max(z0, 0), nl - 1), zc1 = min(max(z0 + 1, 0), nl - 1);
        bool ox0 = (x0 >= 0) && (x0 < nl);
        bool ox1 = (x0 + 1 >= 0) && (x0 + 1 < nl);
        bool oy0 = (y0 >= 0) && (y0 < nl), oy1 = (y0 + 1 >= 0) && (y0 + 1 < nl);
        bool oz0 = (z0 >= 0) && (z0 < nl), oz1 = (z0 + 1 >= 0) && (z0 + 1 < nl);
        int base = b * S_TOT + s0l;
        #pragma unroll
        for (int c = 0; c < 8; ++c) {
            int dx = c & 1, dy = (c >> 1) & 1, dz = c >> 2;
            float w = (dx ? wx1 : wx0) * (dy ? wy1 : wy0) * (dz ? wz1 : wz0);
            bool ok = (dx ? ox1 : ox0) && (dy ? oy1 : oy0) && (dz ? oz1 : oz0);
            int xi = dx ? xc1 : xc0;
            int yi = dy ? yc1 : yc0;
            int zi = dz ? zc1 : zc0;
            // BYTE offset: element ((base+..)*8+h)*32, *2 bytes -> <<6
            int elem = ((base + (zi * nl + yi) * nl + xi) * 8 + h) << 6;
            tbl[t][c] = make_float2(ok ? w * aw : 0.f, __int_as_float(elem));
        }
    }
    __syncthreads();

    // gather: t = (h*8 + corner)*4 + c16; each lane loads 16B (8 bf16 ch)
    const int c16 = t & 3, z = t >> 2, cr = z & 7, h = z >> 3;
    const float2* trow = &tbl[h * 16][cr];     // +9 float2 per point row
    const unsigned cofs = (unsigned)(c16 * 16);
    f32x2 a01 = {0.f, 0.f}, a23 = {0.f, 0.f}, a45 = {0.f, 0.f}, a67 = {0.f, 0.f};
    #pragma unroll
    for (int p = 0; p < 16; ++p) {
        float2 e = trow[p * 9];
        unsigned off = __float_as_uint(e.y) + cofs;
        const uint4 dv = *(const uint4*)((const char*)value + off);
        f32x2 w2 = {e.x, e.x};
        f32x2 v01 = {__uint_as_float(dv.x << 16), __uint_as_float(dv.x & 0xffff0000u)};
        f32x2 v23 = {__uint_as_float(dv.y << 16), __uint_as_float(dv.y & 0xffff0000u)};
        f32x2 v45 = {__uint_as_float(dv.z << 16), __uint_as_float(dv.z & 0xffff0000u)};
        f32x2 v67 = {__uint_as_float(dv.w << 16), __uint_as_float(dv.w & 0xffff0000u)};
        asm("v_pk_fma_f32 %0, %1, %2, %0" : "+v"(a01) : "v"(v01), "v"(w2));
        asm("v_pk_fma_f32 %0, %1, %2, %0" : "+v"(a23) : "v"(v23), "v"(w2));
        asm("v_pk_fma_f32 %0, %1, %2, %0" : "+v"(a45) : "v"(v45), "v"(w2));
        asm("v_pk_fma_f32 %0, %1, %2, %0" : "+v"(a67) : "v"(v67), "v"(w2));
    }
    float acc[8] = {a01.x, a01.y, a23.x, a23.y, a45.x, a45.y, a67.x, a67.y};
    // butterfly reduce over corner (t bits 2..4)
    #pragma unroll
    for (int i = 0; i < 8; ++i) {
        acc[i] += __shfl_xor(acc[i], 4, 64);
        acc[i] += __shfl_xor(acc[i], 8, 64);
        acc[i] += __shfl_xor(acc[i], 16, 64);
    }
    if ((t & 28) == 0) {
        uint4 r;
        r.x = (unsigned)f2bf(acc[0]) | ((unsigned)f2bf(acc[1]) << 16);
        r.y = (unsigned)f2bf(acc[2]) | ((unsigned)f2bf(acc[3]) << 16);
        r.z = (unsigned)f2bf(acc[4]) | ((unsigned)f2bf(acc[5]) << 16);
        r.w = (unsigned)f2bf(acc[6]) | ((unsigned)f2bf(acc[7]) << 16);
        *(uint4*)(out + (size_t)bq * 256 + h * 32 + c16 * 8) = r;
    }
}

// ---------------------------------------------------------------------------
// small multi-head attention (decoder self-attn, Lk=80), online softmax.
__global__ __launch_bounds__(256)
void attn_kernel(const float* __restrict__ Q, const float* __restrict__ K,
                 const float* __restrict__ V, float* __restrict__ O,
                 int Lq, int Lk, float scale, int ldq, int ldk)
{
    const int nqc = (Lq + 3) >> 2;
    const int blk = blockIdx.x;
    const int qc = blk % nqc;
    const int bh = blk / nqc;
    const int h = bh & 7;
    const int b = bh >> 3;
    const int qi0 = qc * 4;
    const int t = threadIdx.x;
    const int c = t & 31, g = t >> 5;

    float qv[4];
    #pragma unroll
    for (int j = 0; j < 4; ++j)
        qv[j] = Q[((size_t)(b * Lq + qi0 + j)) * ldq + h * 32 + c];

    float m[4], l[4], acc[4];
    #pragma unroll
    for (int j = 0; j < 4; ++j) { m[j] = -1e30f; l[j] = 0.f; acc[j] = 0.f; }

    for (int k = g; k < Lk; k += 8) {
        float kv = K[((size_t)(b * Lk + k)) * ldk + h * 32 + c];
        float vv = V[((size_t)(b * Lk + k)) * 256 + h * 32 + c];
        #pragma unroll
        for (int j = 0; j < 4; ++j) {
            float p = qv[j] * kv;
            p += __shfl_xor(p, 16, 32);
            p += __shfl_xor(p, 8, 32);
            p += __shfl_xor(p, 4, 32);
            p += __shfl_xor(p, 2, 32);
            p += __shfl_xor(p, 1, 32);
            float sc = p * scale;
            float mn = fmaxf(m[j], sc);
            float fo = __expf(m[j] - mn);
            float w = __expf(sc - mn);
            l[j] = l[j] * fo + w;
            acc[j] = acc[j] * fo + w * vv;
            m[j] = mn;
        }
    }
    __shared__ float sm[8][4], sl[8][4], sacc[8][4][32];
    if (c == 0) {
        #pragma unroll
        for (int j = 0; j < 4; ++j) { sm[g][j] = m[j]; sl[g][j] = l[j]; }
    }
    #pragma unroll
    for (int j = 0; j < 4; ++j) sacc[g][j][c] = acc[j];
    __syncthreads();
    if (g == 0) {
        #pragma unroll
        for (int j = 0; j < 4; ++j) {
            float M = -1e30f;
            #pragma unroll
            for (int i = 0; i < 8; ++i) M = fmaxf(M, sm[i][j]);
            float L = 0.f, o = 0.f;
            #pragma unroll
            for (int i = 0; i < 8; ++i) {
                float e = __expf(sm[i][j] - M);
                L += sl[i][j] * e;
                o += sacc[i][j][c] * e;
            }
            O[((size_t)(b * Lq + qi0 + j)) * 256 + h * 32 + c] = o / L;
        }
    }
}

// ---------------------------------------------------------------------------
// split-K cross-attention phase 1, MFMA version. 5 waves x 16 queries.
__global__ __launch_bounds__(320)
void xattn_part_kernel(const float* __restrict__ Q,
                       const unsigned short* __restrict__ K,
                       const unsigned short* __restrict__ V,
                       const unsigned long long* __restrict__ mp,
                       float* __restrict__ pm, float* __restrict__ pl,
                       float* __restrict__ po, int Lk, float scale)
{
    const int split = blockIdx.x;
    const int bh = blockIdx.y;
    const int b = bh >> 3, h = bh & 7;
    const int t = threadIdx.x;
    const int wave = t >> 6, lane = t & 63;
    const int l16 = lane & 15, quad = lane >> 4;

    __shared__ unsigned short Ks[128][40];         // 10240 B (pad 40 -> 2-way banks)
    __shared__ unsigned short Vt[32][136];         //  8704 B (V transposed [ch][key])
    __shared__ unsigned short Ps[80][40];          //  6400 B (per-wave-private rows)
    __shared__ unsigned long long Mw[2][128];      //  2048 B [lo/hi][key]

    const int k_base = split * XCHUNK;

    // ---- stage K (row-major) + V (transposed) bf16, zero OOB ----
    for (int idx = t; idx < 512; idx += 320) {
        int key = idx >> 2, cg = (idx & 3) * 8;
        int kg = k_base + key;
        short8 kv = {0, 0, 0, 0, 0, 0, 0, 0};
        short8 vv = {0, 0, 0, 0, 0, 0, 0, 0};
        if (kg < Lk) {
            size_t go = ((size_t)(b * Lk + kg)) * 256 + h * 32 + cg;
            kv = *(const short8*)(K + go);
            vv = *(const short8*)(V + go);
        }
        *(short8*)&Ks[key][cg] = kv;
        #pragma unroll
        for (int j = 0; j < 8; ++j)
            Vt[cg + j][key] = (unsigned short)vv[j];
    }
    if (t < 128) {
        int kg = k_base + t;
        unsigned long long lo = ~0ULL, hi = ~0ULL;
        if (kg < Lk) { lo = mp[2 * kg]; hi = mp[2 * kg + 1]; }
        Mw[0][t] = lo; Mw[1][t] = hi;
    }

    // ---- Q fragment (bf16, pre-scaled): lane holds Q[q=l16][d=quad*8+e] ----
    const int q = wave * 16 + l16;
    short8 qf;
    {
        const float* qp = Q + ((size_t)(b * NQ + q)) * 256 + h * 32 + quad * 8;
        float4 q0 = *(const float4*)qp;
        float4 q1 = *(const float4*)(qp + 4);
        unsigned short* qh = (unsigned short*)&qf;
        qh[0] = f2bf(q0.x * scale); qh[1] = f2bf(q0.y * scale);
        qh[2] = f2bf(q0.z * scale); qh[3] = f2bf(q0.w * scale);
        qh[4] = f2bf(q1.x * scale); qh[5] = f2bf(q1.y * scale);
        qh[6] = f2bf(q1.z * scale); qh[7] = f2bf(q1.w * scale);
    }
    __syncthreads();

    // ---- QK^T: 8 key-tiles of 16 ----
    f32x4 sfr[8];
    const f32x4 zz = {0.f, 0.f, 0.f, 0.f};
    #pragma unroll
    for (int tt = 0; tt < 8; ++tt) {
        short8 kf = *(const short8*)&Ks[tt * 16 + l16][quad * 8];
        sfr[tt] = __builtin_amdgcn_mfma_f32_16x16x32_bf16(kf, qf, zz, 0, 0, 0);
    }

    // ---- mask + softmax (whole 128-key chunk at once) ----
    const unsigned long long* mrow = Mw[wave >> 2];     // waves 0-3: lo, wave 4: hi
    const int qbit = (wave < 4 ? wave * 16 : 0) + l16;
    const int widx = qbit >> 5;
    const int sh = qbit & 31;

    float sc[8][4];
    #pragma unroll
    for (int tt = 0; tt < 8; ++tt) {
        int k0 = tt * 16 + quad * 4;
        uint4 ma = *(const uint4*)&mrow[k0];
        uint4 mb = *(const uint4*)&mrow[k0 + 2];
        unsigned w0 = widx ? ma.y : ma.x;
        unsigned w1 = widx ? ma.w : ma.z;
        unsigned w2 = widx ? mb.y : mb.x;
        unsigned w3 = widx ? mb.w : mb.z;
        sc[tt][0] = ((w0 >> sh) & 1u) ? -1e9f : sfr[tt][0];
        sc[tt][1] = ((w1 >> sh) & 1u) ? -1e9f : sfr[tt][1];
        sc[tt][2] = ((w2 >> sh) & 1u) ? -1e9f : sfr[tt][2];
        sc[tt][3] = ((w3 >> sh) & 1u) ? -1e9f : sfr[tt][3];
    }
    float mx = -1e30f;
    #pragma unroll
    for (int tt = 0; tt < 8; ++tt)
        #pragma unroll
        for (int r = 0; r < 4; ++r) mx = fmaxf(mx, sc[tt][r]);
    mx = fmaxf(mx, __shfl_xor(mx, 16, 64));
    mx = fmaxf(mx, __shfl_xor(mx, 32, 64));
    float sum = 0.f;
    #pragma unroll
    for (int tt = 0; tt < 8; ++tt)
        #pragma unroll
        for (int r = 0; r < 4; ++r) {
            sc[tt][r] = __expf(sc[tt][r] - mx);
            sum += sc[tt][r];
        }
    sum += __shfl_xor(sum, 16, 64);
    sum += __shfl_xor(sum, 32, 64);

    // ---- PV: per 32-key slice, P->LDS (wave-private rows) -> MFMA ----
    f32x4 oacc[2] = {zz, zz};
    #pragma unroll
    for (int s = 0; s < 4; ++s) {
        #pragma unroll
        for (int tt = 0; tt < 2; ++tt) {
            int T = s * 2 + tt;
            unsigned plo = (unsigned)f2bf(sc[T][0]) | ((unsigned)f2bf(sc[T][1]) << 16);
            unsigned phi = (unsigned)f2bf(sc[T][2]) | ((unsigned)f2bf(sc[T][3]) << 16);
            unsigned* dst = (unsigned*)&Ps[q][tt * 16 + quad * 4];
            dst[0] = plo; dst[1] = phi;
        }
        asm volatile("" ::: "memory");   // keep LDS write->read order
        short8 pf = *(const short8*)&Ps[q][quad * 8];
        short8 vf0 = *(const short8*)&Vt[l16][s * 32 + quad * 8];
        short8 vf1 = *(const short8*)&Vt[16 + l16][s * 32 + quad * 8];
        oacc[0] = __builtin_amdgcn_mfma_f32_16x16x32_bf16(vf0, pf, oacc[0], 0, 0, 0);
        oacc[1] = __builtin_amdgcn_mfma_f32_16x16x32_bf16(vf1, pf, oacc[1], 0, 0, 0);
    }

    // ---- write partials: O^T lane holds ch=c*16+quad*4+r for q=l16 ----
    const size_t obase = ((size_t)bh * NSPLIT + split) * NQ;
    #pragma unroll
    for (int c = 0; c < 2; ++c)
        #pragma unroll
        for (int r = 0; r < 4; ++r)
            po[(obase + q) * 32 + c * 16 + quad * 4 + r] = oacc[c][r];
    if (quad == 0) { pm[obase + q] = mx; pl[obase + q] = sum; }
}

// phase 2: merge NSPLIT partials per (b,h,q) -> O[B,NQ,256]
__global__ __launch_bounds__(64)
void xattn_merge_kernel(const float* __restrict__ pm, const float* __restrict__ pl,
                        const float* __restrict__ po, float* __restrict__ O)
{
    const int idx = blockIdx.x;
    const int bh = idx / NQ, q = idx - bh * NQ;
    const int b = bh >> 3, h = bh & 7;
    const int tt = threadIdx.x;
    if (tt >= 32) return;
    const int c = tt;
    float M = -1e30f;
    for (int s = 0; s < NSPLIT; ++s)
        M = fmaxf(M, pm[((size_t)bh * NSPLIT + s) * NQ + q]);
    float L = 0.f, o = 0.f;
    for (int s = 0; s < NSPLIT; ++s) {
        size_t base = ((size_t)bh * NSPLIT + s) * NQ + q;
        float e = __expf(pm[base] - M);
        L += pl[base] * e;
        o += po[base * 32 + c] * e;
    }
    O[((size_t)(b * NQ + q)) * 256 + h * 32 + c] = o / L;
}

// ---------------------------------------------------------------------------
extern "C" void kernel_launch(void* const* d_in, const int* in_sizes, int n_in,
                              void* d_out, int out_size, void* d_ws, size_t ws_size,
                              hipStream_t stream)
{
    const float* src       = (const float*)d_in[0];
    const float* pos       = (const float*)d_in[1];
    const float* lvl_pos   = (const float*)d_in[2];
    const float* tgt       = (const float*)d_in[3];
    const float* query_pos = (const float*)d_in[4];
    const float* eow  = (const float*)d_in[6];
    const float* eob  = (const float*)d_in[7];
    const float* eaw  = (const float*)d_in[8];
    const float* eab  = (const float*)d_in[9];
    const float* evw  = (const float*)d_in[10];
    const float* evb  = (const float*)d_in[11];
    const float* eouw = (const float*)d_in[12];
    const float* eoub = (const float*)d_in[13];
    const float* el1g = (const float*)d_in[14];
    const float* el1b = (const float*)d_in[15];
    const float* ef1w = (const float*)d_in[16];
    const float* ef1b = (const float*)d_in[17];
    const float* ef2w = (const float*)d_in[18];
    const float* ef2b = (const float*)d_in[19];
    const float* el2g = (const float*)d_in[20];
    const float* el2b = (const float*)d_in[21];
    const float* dsiw = (const float*)d_in[22];
    const float* dsib = (const float*)d_in[23];
    const float* dsow = (const float*)d_in[24];
    const float* dsob = (const float*)d_in[25];
    const float* dciw = (const float*)d_in[26];
    const float* dcib = (const float*)d_in[27];
    const float* dcow = (const float*)d_in[28];
    const float* dcob = (const float*)d_in[29];
    const float* dl1g = (const float*)d_in[30];
    const float* dl1b = (const float*)d_in[31];
    const float* dl2g = (const float*)d_in[32];
    const float* dl2b = (const float*)d_in[33];
    const float* dl3g = (const float*)d_in[34];
    const float* dl3b = (const float*)d_in[35];
    const float* df1w = (const float*)d_in[36];
    const float* df1b = (const float*)d_in[37];
    const float* df2w = (const float*)d_in[38];
    const float* df2b = (const float*)d_in[39];
    const unsigned char* amask = (const unsigned char*)d_in[40];

    const int MBS = B_SZ * S_TOT;                  // 31590
    const size_t nBSC = (size_t)MBS * 256;
    const size_t nP   = (size_t)MP * 256;
    const size_t nFFA = (size_t)MBS * 512 + 16384; // packed off|aw ; aliased by b_hs

    float* ws = (float*)d_ws;
    float* f_out = ws; ws += nP;                   // encoder state / memory (fp32)
    float* f_mlp = ws; ws += nP;                   // (unused in encoder now)
    float* f_ffa = ws; ws += nFFA;                 // f_offaw ; aliased by b_hs
    float* f_offaw = f_ffa;                        // [MBS,512] enc off|aw ; dec cross-K bf16
    float* f_val = ws; ws += nP;                   // dec cross-V bf16
    float* d_q   = ws; ws += 40960;
    float* d_qkp = ws; ws += 81920;                // packed self-attn Q|K [160,512]
    float* d_sq  = ws; ws += 40960;
    float* d_sv  = ws; ws += 40960;
    float* d_ao  = ws; ws += 40960;
    float* d_pr  = ws; ws += 40960;
    float* d_h   = ws; ws += 163840;
    float* x_pm  = ws; ws += (size_t)16 * XSPLIT * NQ;
    float* x_pl  = ws; ws += (size_t)16 * XSPLIT * NQ;
    float* x_po  = ws; ws += (size_t)16 * XSPLIT * NQ * 32;
    unsigned long long* x_mp = (unsigned long long*)ws; ws += 2 * 16384;  // packed mask
    float* f_fb  = ws; ws += 6 * 512;              // fused enc off|aw bias

    unsigned short* bws = (unsigned short*)ws;
    unsigned short* b_mlp  = bws; bws += nP;            // bf16(state+pos)/dec memory+lvl_pos
    unsigned short* b_out  = bws; bws += nP;            // bf16 encoder state
    unsigned short* w_eoaw = bws; bws += (size_t)6 * 512 * 256;   // fused off|aw weights
    unsigned short* w_evw  = bws; bws += (size_t)6 * 256 * 256;
    unsigned short* w_eouw = bws; bws += (size_t)6 * 256 * 256;
    unsigned short* w_ef1  = bws; bws += (size_t)6 * 1024 * 256;
    unsigned short* w_ef2  = bws; bws += (size_t)6 * 256 * 1024;
    unsigned short* w_dciw = bws; bws += (size_t)6 * 768 * 256;

    // aliases (disjoint lifetimes):
    unsigned short* b_hs   = (unsigned short*)f_ffa;   // fc1 out (MP*1024 bf16)
    unsigned short* b_samp = b_mlp;                    // deform out (MBS*256 bf16)
    unsigned short* b_val  = (unsigned short*)x_pm;    // bf16 deform value (encoder-only;
                                                       // x_pm/x_pl/x_po = 22.3MB >= 16.2MB)
    unsigned short* b_xk   = (unsigned short*)f_offaw; // bf16 decoder cross-K [MBS,256]
    unsigned short* b_xv   = (unsigned short*)f_val;   // bf16 decoder cross-V [MBS,256]

    auto gemmb = [&](const unsigned short* A, const unsigned short* W, const float* bb,
                     void* Y, int M, int N, int K, int mode) {
        dim3 grid(N / 128, (M + 127) / 128);
        gemm_bf16_kernel<<<grid, dim3(256), 0, stream>>>(A, W, bb, Y, M, N, K, mode);
    };
    auto gemmln = [&](const unsigned short* A, const unsigned short* W, const float* bb,
                      const float* lg, const float* lb, const float* padd,
                      unsigned short* oadd, int M, int K) {
        gemm_ln_kernel<<<(M + 63) / 64, dim3(256), 0, stream>>>(
            A, W, bb, lg, lb, f_out, b_out, padd, oadd, M, K);
    };
    auto gemms = [&](const float* X, const float* Xadd, const float* W, const float* bb,
                     float* Y, int M, int N, int K, int relu) {
        dim3 grid(N / 64, (M + 63) / 64);
        gemm_bias_kernel<<<grid, dim3(256), 0, stream>>>(X, Xadd, W, bb, Y, M, N, K, relu);
    };
    auto cast = [&](const float* x, unsigned short* o, size_t n) {
        int n4c = (int)(n / 4);
        cast_bf16_kernel<<<(n4c + 255) / 256, 256, 0, stream>>>(x, o, n4c);
    };

    const int n4 = (int)(nBSC / 4);
    const float scale = 0.17677669529663687f;

    // one-time prep
    {
        const int nf4 = 6 * 512 * 256 / 4;
        cast_fuse_w_kernel<<<(nf4 + 255) / 256, 256, 0, stream>>>(eow, eaw, w_eoaw);
        fuse_bias_kernel<<<6, 512, 0, stream>>>(eob, eab, f_fb);
        mask_pack_kernel<<<(S_TOT + 255) / 256, 256, 0, stream>>>(amask, x_mp, S_TOT);
    }
    cast(evw,  w_evw,  (size_t)6 * 256 * 256);
    cast(eouw, w_eouw, (size_t)6 * 256 * 256);
    cast(ef1w, w_ef1,  (size_t)6 * 1024 * 256);
    cast(ef2w, w_ef2,  (size_t)6 * 256 * 1024);
    cast(dciw, w_dciw, (size_t)6 * 768 * 256);

    init_enc_kernel<<<(n4 + 255) / 256, 256, 0, stream>>>(src, pos, f_out, b_out, b_mlp, n4);

    // ---------------- encoder ----------------
    for (int i = 0; i < 6; ++i) {
        gemmb(b_mlp, w_eoaw + (size_t)i * 512 * 256, f_fb + i * 512, f_offaw, MBS, 512, 256, 0);
        gemmb(b_out, w_evw + (size_t)i * 256 * 256, evb + i * 256, b_val, MBS, 256, 256, 2);
        deform_kernel<<<MBS, 256, 0, stream>>>(f_offaw, b_val, b_samp);
        // fused out-proj + residual + LN1 -> f_out, b_out
        gemmln(b_samp, w_eouw + (size_t)i * 256 * 256, eoub + i * 256,
               el1g + i * 256, el1b + i * 256, nullptr, nullptr, MBS, 256);
        gemmb(b_out, w_ef1 + (size_t)i * 1024 * 256, ef1b + i * 1024, b_hs, MBS, 1024, 256, 1);
        // fused fc2 + residual + LN2 -> f_out, b_out, b_mlp = bf16(out + pos/lvl_pos)
        gemmln(b_hs, w_ef2 + (size_t)i * 256 * 1024, ef2b + i * 256,
               el2g + i * 256, el2b + i * 256, (i < 5 ? pos : lvl_pos), b_mlp, MBS, 1024);
    }

    // ---------------- decoder ----------------
    hipMemcpyAsync(d_q, tgt, 40960 * sizeof(float), hipMemcpyDeviceToDevice, stream);

    for (int i = 0; i < 6; ++i) {
        const float* siw = dsiw + (size_t)i * 768 * 256;
        const float* sib = dsib + (size_t)i * 768;
        gemms(d_q, query_pos, siw, sib, d_qkp, 160, 512, 256, 0);        // packed Q|K
        gemms(d_q, nullptr, siw + 512 * 256, sib + 512, d_sv, 160, 256, 256, 0);
        attn_kernel<<<B_SZ * 8 * (NQ / 4), 256, 0, stream>>>(
            d_qkp, d_qkp + 256, d_sv, d_ao, NQ, NQ, scale, 512, 512);
        gemms(d_ao, nullptr, dsow + (size_t)i * 256 * 256, dsob + i * 256, d_pr, 160, 256, 256, 0);
        ln_res_kernel<<<40, 256, 0, stream>>>(d_q, d_pr, dl2g + i * 256, dl2b + i * 256,
                                              d_q, (unsigned short*)nullptr,
                                              (const float*)nullptr, (unsigned short*)nullptr, 160);

        const float* cib = dcib + (size_t)i * 768;
        gemms(d_q, query_pos, dciw + (size_t)i * 768 * 256, cib, d_sq, 160, 256, 256, 0);
        gemmb(b_mlp, w_dciw + (size_t)i * 768 * 256 + 256 * 256, cib + 256,
              b_xk, MBS, 256, 256, 2);                                         // cross-K bf16
        gemmb(b_out, w_dciw + (size_t)i * 768 * 256 + 512 * 256, cib + 512,
              b_xv, MBS, 256, 256, 2);                                         // cross-V bf16
        xattn_part_kernel<<<dim3(NSPLIT, 16), 320, 0, stream>>>(
            d_sq, b_xk, b_xv, x_mp, x_pm, x_pl, x_po, S_TOT, scale);
        xattn_merge_kernel<<<16 * NQ, 64, 0, stream>>>(x_pm, x_pl, x_po, d_ao);
        gemms(d_ao, nullptr, dcow + (size_t)i * 256 * 256, dcob + i * 256, d_pr, 160, 256, 256, 0);
        ln_res_kernel<<<40, 256, 0, stream>>>(d_q, d_pr, dl1g + i * 256, dl1b + i * 256,
                                              d_q, (unsigned short*)nullptr,
                                              (const float*)nullptr, (unsigned short*)nullptr, 160);

        gemms(d_q, nullptr, df1w + (size_t)i * 1024 * 256, df1b + i * 1024, d_h, 160, 1024, 256, 1);
        gemms(d_h, nullptr, df2w + (size_t)i * 256 * 1024, df2b + i * 256, d_pr, 160, 256, 1024, 0);
        ln_res_kernel<<<40, 256, 0, stream>>>(d_q, d_pr, dl3g + i * 256, dl3b + i * 256,
                                              d_q, (unsigned short*)nullptr,
                                              (const float*)nullptr, (unsigned short*)nullptr, 160);
    }

    hipMemcpyAsync(d_out, d_q, 40960 * sizeof(float), hipMemcpyDeviceToDevice, stream);
}